// Round 4
// baseline (654.511 us; speedup 1.0000x reference)
//
#include <hip/hip_runtime.h>
#include <hip/hip_bf16.h>
#include <stdint.h>

#define HF 256   // H == F == 256
#define GG 50    // G

typedef __attribute__((ext_vector_type(8))) short bf16x8;
typedef __attribute__((ext_vector_type(4))) short bf16x4;
typedef __attribute__((ext_vector_type(4))) float f32x4;
typedef float f32x4a __attribute__((ext_vector_type(4), aligned(4)));  // dword-aligned vec4 load

// packed f32x2 -> bf16x2 (v_cvt_pk_bf16_f32 on gfx950), low short = a
__device__ __forceinline__ uint32_t f2bf2u(float a, float b){
    __hip_bfloat162 h = __float22bfloat162_rn(make_float2(a, b));
    union { __hip_bfloat162 h; uint32_t u; } v; v.h = h; return v.u;
}
__device__ __forceinline__ float bf2f(short s){
    union { uint32_t u; float f; } v; v.u = ((uint32_t)(uint16_t)s) << 16;
    return v.f;
}
// shifted softplus: ln(1+e^x) - ln2 (safe for |x| < ~80; GEMM outputs are O(+-6))
__device__ __forceinline__ float ssp_f(float x){
    float e = __builtin_amdgcn_exp2f(x * 1.44269504088896341f);
    return 0.69314718055994531f * __builtin_amdgcn_logf(1.0f + e)
         - 0.69314718055994531f;
}

// ---------------------------------------------------------------------------
// prep_kernel: [pack weights] + [x fp32->bf16] + [degree histogram] + [agg=0]
// ---------------------------------------------------------------------------
__device__ __forceinline__ void pack_natural(const float* __restrict__ B,
                                             short* __restrict__ Bp,
                                             int idx, int KT, int kmax)
{
    int lane = idx & 63;
    int kt   = (idx >> 6) & (KT - 1);
    int ntg  = idx >> (6 + (KT == 2 ? 1 : 3));
    int col  = ntg * 16 + (lane & 15);
    int k0   = kt * 32 + (lane >> 4) * 8;
    uint32_t u[4];
#pragma unroll
    for (int jj = 0; jj < 4; ++jj) {
        int ka = k0 + 2*jj, kb = ka + 1;
        float a = (ka < kmax) ? B[(size_t)ka * HF + col] : 0.f;
        float b = (kb < kmax) ? B[(size_t)kb * HF + col] : 0.f;
        u[jj] = f2bf2u(a, b);
    }
    *(uint4*)&Bp[(size_t)idx * 8] = *(uint4*)u;
}

__global__ __launch_bounds__(256)
void prep_kernel(const float* __restrict__ w1, const float* __restrict__ b1,
                 const float* __restrict__ w2,
                 const float* __restrict__ lin1, const float* __restrict__ lin2,
                 short* __restrict__ w1p, short* __restrict__ w2p,
                 short* __restrict__ lin1p, short* __restrict__ lin2p,
                 const float* __restrict__ x, short* __restrict__ x_bf, int nx8,
                 const int* __restrict__ eidx, int* __restrict__ cnt, int E,
                 float* __restrict__ agg, int nAgg4, int gConv, int gHist)
{
    int b = blockIdx.x, tid = threadIdx.x;
    if (b < 8) {                       // w1p with b1 folded at k==GG
        int idx  = b * 256 + tid;
        int lane = idx & 63;
        int kt   = (idx >> 6) & 1;
        int ntg  = idx >> 7;
        int col  = ntg * 16 + (lane & 15);
        int k0   = kt * 32 + (lane >> 4) * 8;
        uint32_t u[4];
#pragma unroll
        for (int jj = 0; jj < 4; ++jj) {
            int ka = k0 + 2*jj, kb = ka + 1;
            float va = (ka < GG) ? w1[(size_t)ka * HF + col]
                                 : ((ka == GG) ? b1[col] : 0.f);
            float vb = (kb < GG) ? w1[(size_t)kb * HF + col]
                                 : ((kb == GG) ? b1[col] : 0.f);
            u[jj] = f2bf2u(va, vb);
        }
        *(uint4*)&w1p[(size_t)idx * 8] = *(uint4*)u;
    } else if (b < 40) {               // w2p: permuted k axis
        int idx = (b - 8) * 256 + tid;
        int lane = idx & 63;
        int kt   = (idx >> 6) & 7;
        int ntg  = idx >> 9;
        int col  = ntg * 16 + (lane & 15);
        int s0   = kt * 32 + (lane >> 4) * 8;
        uint32_t u[4];
#pragma unroll
        for (int jj = 0; jj < 4; ++jj) {
            int sa = s0 + 2*jj, sb = sa + 1;
            int fa = (sa >> 6) * 64 + (sa & 3) * 16 + ((sa & 63) >> 2);
            int fb = (sb >> 6) * 64 + (sb & 3) * 16 + ((sb & 63) >> 2);
            u[jj] = f2bf2u(w2[(size_t)fa * HF + col], w2[(size_t)fb * HF + col]);
        }
        *(uint4*)&w2p[(size_t)idx * 8] = *(uint4*)u;
    } else if (b < 72) {
        pack_natural(lin1, lin1p, (b - 40) * 256 + tid, 8, HF);
    } else if (b < 104) {
        pack_natural(lin2, lin2p, (b - 72) * 256 + tid, 8, HF);
    } else if (b < 104 + gConv) {      // x -> bf16, 8 elems/thread
        int idx = (b - 104) * 256 + tid;
        if (idx < nx8) {
            const float* xp = x + (size_t)idx * 8;
            float4 p0 = *(const float4*)(xp);
            float4 p1 = *(const float4*)(xp + 4);
            uint32_t u[4] = { f2bf2u(p0.x, p0.y), f2bf2u(p0.z, p0.w),
                              f2bf2u(p1.x, p1.y), f2bf2u(p1.z, p1.w) };
            *(uint4*)&x_bf[(size_t)idx * 8] = *(uint4*)u;
        }
    } else if (b < 104 + gConv + gHist) {   // histogram
        int e = (b - 104 - gConv) * 256 + tid;
        if (e < E) atomicAdd(&cnt[eidx[e]], 1);
    } else {                           // agg zero (float4 granular)
        int idx = (b - 104 - gConv - gHist) * 256 + tid;
        if (idx < nAgg4) ((float4*)agg)[idx] = make_float4(0.f, 0.f, 0.f, 0.f);
    }
}

// ---------------------------------------------------------------------------
// gemm_scan_kernel: blocks [0, gNode) do the y_p GEMM (M-tile 32);
// block gNode runs the 1-block exclusive scan CONCURRENTLY.
// ---------------------------------------------------------------------------
__global__ __launch_bounds__(256)
void gemm_scan_kernel(const short* __restrict__ x_bf, const short* __restrict__ lin1p,
                      short* __restrict__ y_p, int N,
                      const int* __restrict__ cnt, int* __restrict__ row,
                      int* __restrict__ cursor, int E, int gNode)
{
    const int tid = threadIdx.x;
    if ((int)blockIdx.x >= gNode) {    // ---- scan block
        __shared__ int part[256];
        const int CH = (N + 255) / 256;
        int lo = tid * CH;
        int hi = min(lo + CH, N);
        int s = 0;
        for (int n = lo; n < hi; ++n) s += cnt[n];
        part[tid] = s;
        __syncthreads();
        for (int off = 1; off < 256; off <<= 1) {
            int v = (tid >= off) ? part[tid - off] : 0;
            __syncthreads();
            part[tid] += v;
            __syncthreads();
        }
        int acc = part[tid] - s;   // exclusive
        for (int n = lo; n < hi; ++n) {
            row[n] = acc; cursor[n] = acc;
            acc += cnt[n];
        }
        if (tid == 255) row[N] = E;
        return;
    }
    // ---- y_p GEMM
    const int lane = tid & 63;
    const int w    = tid >> 6;
    const int l15  = lane & 15;
    const int quad = lane >> 4;
    const int row0 = blockIdx.x * 32;

    f32x4 acc[2][4];
#pragma unroll
    for (int mt = 0; mt < 2; ++mt)
#pragma unroll
        for (int nt = 0; nt < 4; ++nt) acc[mt][nt] = (f32x4){0.f,0.f,0.f,0.f};

#pragma unroll 2
    for (int kt = 0; kt < 8; ++kt) {
        bf16x8 af[2];
#pragma unroll
        for (int mt = 0; mt < 2; ++mt) {
            int r = row0 + mt * 16 + l15;
            int rl = (r < N) ? r : 0;
            af[mt] = *(const bf16x8*)&x_bf[(size_t)rl * HF + kt * 32 + quad * 8];
        }
#pragma unroll
        for (int nt = 0; nt < 4; ++nt) {
            bf16x8 bfr = *(const bf16x8*)&lin1p[(size_t)(((w*4+nt)*8+kt)*64+lane)*8];
#pragma unroll
            for (int mt = 0; mt < 2; ++mt)
                acc[mt][nt] = __builtin_amdgcn_mfma_f32_16x16x32_bf16(af[mt], bfr, acc[mt][nt], 0, 0, 0);
        }
    }
#pragma unroll
    for (int mt = 0; mt < 2; ++mt) {
#pragma unroll
        for (int r = 0; r < 4; ++r) {
            int row_ = row0 + mt * 16 + quad * 4 + r;
            if (row_ < N) {
                uint2 u = make_uint2(f2bf2u(acc[mt][0][r], acc[mt][1][r]),
                                     f2bf2u(acc[mt][2][r], acc[mt][3][r]));
                *(uint2*)&y_p[(size_t)row_ * HF + w * 64 + l15 * 4] = u;
            }
        }
    }
}

// ---------------------------------------------------------------------------
// scatter_kernel: counting-sort scatter using cursor from the scan
// ---------------------------------------------------------------------------
__global__ __launch_bounds__(256)
void scatter_kernel(const int* __restrict__ eidx, int* __restrict__ cursor,
                    int* __restrict__ perm, int E)
{
    int e = blockIdx.x * 256 + threadIdx.x;
    if (e < E) {
        int pos = atomicAdd(&cursor[eidx[e]], 1);
        perm[pos] = e;
    }
}

// ---------------------------------------------------------------------------
// node2_kernel: out = ssp(agg@lin2 + b) + x   (M-tile 32)
// ---------------------------------------------------------------------------
__global__ __launch_bounds__(256)
void node2_kernel(const float* __restrict__ agg, const short* __restrict__ lin2p,
                  const float* __restrict__ bias, const float* __restrict__ x,
                  float* __restrict__ out, int N)
{
    const int tid  = threadIdx.x;
    const int lane = tid & 63;
    const int w    = tid >> 6;
    const int l15  = lane & 15;
    const int quad = lane >> 4;
    const int row0 = blockIdx.x * 32;

    f32x4 acc[2][4];
#pragma unroll
    for (int mt = 0; mt < 2; ++mt)
#pragma unroll
        for (int nt = 0; nt < 4; ++nt) acc[mt][nt] = (f32x4){0.f,0.f,0.f,0.f};

#pragma unroll 2
    for (int kt = 0; kt < 8; ++kt) {
        bf16x8 af[2];
#pragma unroll
        for (int mt = 0; mt < 2; ++mt) {
            int r = row0 + mt * 16 + l15;
            int rl = (r < N) ? r : 0;
            const float* ap = agg + (size_t)rl * HF + kt * 32 + quad * 8;
            float4 p0 = *(const float4*)(ap);
            float4 p1 = *(const float4*)(ap + 4);
            union { uint32_t u[4]; bf16x8 v; } c;
            c.u[0] = f2bf2u(p0.x, p0.y); c.u[1] = f2bf2u(p0.z, p0.w);
            c.u[2] = f2bf2u(p1.x, p1.y); c.u[3] = f2bf2u(p1.z, p1.w);
            af[mt] = c.v;
        }
#pragma unroll
        for (int nt = 0; nt < 4; ++nt) {
            bf16x8 bfr = *(const bf16x8*)&lin2p[(size_t)(((w*4+nt)*8+kt)*64+lane)*8];
#pragma unroll
            for (int mt = 0; mt < 2; ++mt)
                acc[mt][nt] = __builtin_amdgcn_mfma_f32_16x16x32_bf16(af[mt], bfr, acc[mt][nt], 0, 0, 0);
        }
    }
    float bs[4];
#pragma unroll
    for (int nt = 0; nt < 4; ++nt) bs[nt] = bias[w * 64 + nt * 16 + l15];
#pragma unroll
    for (int mt = 0; mt < 2; ++mt) {
#pragma unroll
        for (int r = 0; r < 4; ++r) {
            int row_ = row0 + mt * 16 + quad * 4 + r;
            if (row_ < N) {
#pragma unroll
                for (int nt = 0; nt < 4; ++nt) {
                    int f = w * 64 + nt * 16 + l15;
                    float v = ssp_f(acc[mt][nt][r] + bs[nt]) + x[(size_t)row_ * HF + f];
                    out[(size_t)row_ * HF + f] = v;
                }
            }
        }
    }
}

// ---------------------------------------------------------------------------
// edge_mfma (persistent): grid = min(nT,1000) blocks; each block loops over
// tiles strided by gridDim, software-pipelining the next tile's inputs
// (perm -> eidx/ew -> raw ea floats -> y_p rows) under the current tile's
// compute. w1p/w2p B-fragments are loop-invariant -> hoisted into registers
// (loaded once per block; removes per-tile L2 latency from GEMM1/GEMM2).
// Barriers: barA (hid ready), barB (hid dead), barEnd (msgT/runnode recycle).
// St only depends on the ballot -> built before barA (no barC). msgT is
// wave-private (wave w writes & reads rows [64w,64w+64)) -> no barrier needed
// between epilogue write and GEMM3 read.
// ---------------------------------------------------------------------------
__device__ __forceinline__ void issue_ea(const float* __restrict__ ea, int eLsrc,
                                         int l15, int quad,
                                         f32x4a (&rp0)[4], f32x4a (&rp1)[4],
                                         f32x4a (&rq0)[4], f32x4a (&rq1)[4])
{
#pragma unroll
    for (int mt = 0; mt < 4; ++mt) {
        int rp = __shfl(eLsrc, mt * 16 + l15);
        const float* er = ea + (size_t)rp * GG;
        rp0[mt] = *(const f32x4a*)(er + quad * 8);
        rp1[mt] = *(const f32x4a*)(er + quad * 8 + 4);
        if (quad < 2) {
            rq0[mt] = *(const f32x4a*)(er + 32 + quad * 8);
            rq1[mt] = *(const f32x4a*)(er + 36 + quad * 8);
        } else if (quad == 2) {
            float2 q = *(const float2*)(er + 48);
            rq0[mt][0] = q.x; rq0[mt][1] = q.y;
        }
    }
}

__device__ __forceinline__ void cvt_a1(int quad,
                                       const f32x4a (&rp0)[4], const f32x4a (&rp1)[4],
                                       const f32x4a (&rq0)[4], const f32x4a (&rq1)[4],
                                       bf16x8 (&a1)[4][2])
{
#pragma unroll
    for (int mt = 0; mt < 4; ++mt) {
        union { uint32_t u[4]; bf16x8 v; } ca;
        ca.u[0] = f2bf2u(rp0[mt][0], rp0[mt][1]); ca.u[1] = f2bf2u(rp0[mt][2], rp0[mt][3]);
        ca.u[2] = f2bf2u(rp1[mt][0], rp1[mt][1]); ca.u[3] = f2bf2u(rp1[mt][2], rp1[mt][3]);
        a1[mt][0] = ca.v;
        union { uint32_t u[4]; bf16x8 v; } cb;
        if (quad < 2) {
            cb.u[0] = f2bf2u(rq0[mt][0], rq0[mt][1]); cb.u[1] = f2bf2u(rq0[mt][2], rq0[mt][3]);
            cb.u[2] = f2bf2u(rq1[mt][0], rq1[mt][1]); cb.u[3] = f2bf2u(rq1[mt][2], rq1[mt][3]);
        } else if (quad == 2) {
            cb.u[0] = f2bf2u(rq0[mt][0], rq0[mt][1]);
            cb.u[1] = 0x00003F80u;      // k=50 -> 1.0 (bias row), k=51 -> 0
            cb.u[2] = 0u; cb.u[3] = 0u;
        } else {
            cb.u[0] = 0u; cb.u[1] = 0u; cb.u[2] = 0u; cb.u[3] = 0u;
        }
        a1[mt][1] = cb.v;
    }
}

__device__ __forceinline__ void issue_yv(const short* __restrict__ y_p, int jvsrc,
                                         int w, int l15, int quad, bf16x4 (&yv)[4][4])
{
#pragma unroll
    for (int mt = 0; mt < 4; ++mt)
#pragma unroll
        for (int r = 0; r < 4; ++r) {
            int j = __shfl(jvsrc, mt * 16 + quad * 4 + r);
            yv[mt][r] = *(const bf16x4*)&y_p[(size_t)j * HF + w * 64 + l15 * 4];
        }
}

__global__ __launch_bounds__(256, 3)
void edge_mfma(const float* __restrict__ ea, const int* __restrict__ eidx,
               const float* __restrict__ ew,
               const short* __restrict__ w1p,
               const short* __restrict__ w2p, const float* __restrict__ b2,
               const short* __restrict__ y_p, const int* __restrict__ perm,
               const int* __restrict__ rowp,
               float* __restrict__ agg, int E, int grid64)
{
    __shared__ short smem[19584];      // 39168 B
    short* hid  = smem;                // [64][264] (phase 1-2: 33792 B)
    short* msgT = smem;                // [256][72] (phase 3+, aliases hid)
    short* St   = smem + 18432;        // [16][72]  (outside hid/msgT)
    __shared__ int s_runnode[64];
    __shared__ unsigned char s_runcomp[64];

    const int tid  = threadIdx.x;
    const int lane = tid & 63;
    const int w    = tid >> 6;
    const int l15  = lane & 15;
    const int quad = lane >> 4;

    // ---- loop-invariant weight fragments -> registers
    bf16x8 w1f[2][4];
#pragma unroll
    for (int kt = 0; kt < 2; ++kt)
#pragma unroll
        for (int nt = 0; nt < 4; ++nt)
            w1f[kt][nt] = *(const bf16x8*)&w1p[(size_t)(((w*4+nt)*2+kt)*64+lane)*8];
    bf16x8 w2f[8][4];
#pragma unroll
    for (int kt = 0; kt < 8; ++kt)
#pragma unroll
        for (int nt = 0; nt < 4; ++nt)
            w2f[kt][nt] = *(const bf16x8*)&w2p[(size_t)(((w*4+nt)*8+kt)*64+lane)*8];
    float bias2[4];
#pragma unroll
    for (int nt = 0; nt < 4; ++nt) bias2[nt] = b2[w * 64 + nt * 16 + l15];

    // ---- prologue: prefetch tile 0's inputs
    int e0 = blockIdx.x * 64;
    int pp = e0 + lane;
    int eL = 0, iv = -1;
    float c = 0.f;
    if (pp < E) {
        eL = perm[pp];
        iv = eidx[eL];
        float d0 = ew[eL*3+0], d1 = ew[eL*3+1], d2 = ew[eL*3+2];
        float d = sqrtf(d0*d0 + d1*d1 + d2*d2);
        c = (d <= 2.0f) ? 0.5f * (__cosf(d * 1.57079632679489662f) + 1.0f) : 0.f;
    }
    int jv = eidx[E + eL];
    f32x4a rp0[4], rp1[4], rq0[4], rq1[4];
    issue_ea(ea, eL, l15, quad, rp0, rp1, rq0, rq1);
    bf16x4 yv[4][4];
    issue_yv(y_p, jv, w, l15, quad, yv);

    for (; e0 < E; e0 += grid64) {
        // ---- raw ea -> bf16 A-fragments (loads arrived during prev tile)
        bf16x8 a1[4][2];
        cvt_a1(quad, rp0, rp1, rq0, rq1, a1);

        // ---- per-wave run metadata (redundant across waves; no barrier)
        int ivn_ = __shfl_down(iv, 1);
        bool flag = (lane == 63) || (iv != ivn_);     // run ends at this lane
        unsigned long long bm = __ballot(flag);
        const int runcnt = (int)__popcll(bm);
        if (w == 0 && flag) {
            int rid = (int)__popcll(bm & ((1ull << lane) - 1ull));
            s_runnode[rid] = iv;
            int comp = 0;
            if (iv >= 0) {
                int lo = rowp[iv], hi = rowp[iv + 1];
                comp = (lo >= e0 && hi <= e0 + 64) ? 1 : 0;
            }
            s_runcomp[rid] = (unsigned char)comp;
        }
        // St group 0 (depends only on bm; visible after barA; read at GEMM3)
        {
            int e   = tid & 63;
            int rb  = tid >> 6;
            int rid = (int)__popcll(bm & ((1ull << e) - 1ull));
#pragma unroll
            for (int q = 0; q < 4; ++q) {
                int r = rb + q * 4;
                St[r * 72 + e] = (rid == r) ? (short)0x3F80 : (short)0;
            }
        }

        // ---- issue next tile's perm (independent load, long slack)
        const int e0n = e0 + grid64;
        const int ppn = e0n + lane;
        int eLn = (ppn < E) ? perm[ppn] : 0;

        // ---- GEMM1: [64e x 64k] @ [64k x 64f]  (register B)
        f32x4 acc1[4][4];
#pragma unroll
        for (int mt = 0; mt < 4; ++mt)
#pragma unroll
            for (int nt = 0; nt < 4; ++nt) acc1[mt][nt] = (f32x4){0.f,0.f,0.f,0.f};
#pragma unroll
        for (int kt = 0; kt < 2; ++kt)
#pragma unroll
            for (int nt = 0; nt < 4; ++nt)
#pragma unroll
                for (int mt = 0; mt < 4; ++mt)
                    acc1[mt][nt] = __builtin_amdgcn_mfma_f32_16x16x32_bf16(a1[mt][kt], w1f[kt][nt], acc1[mt][nt], 0, 0, 0);

        // ssp -> hid (bf16, col' = w*64 + l15*4 + nt)
#pragma unroll
        for (int mt = 0; mt < 4; ++mt) {
#pragma unroll
            for (int r = 0; r < 4; ++r) {
                int e = mt * 16 + quad * 4 + r;
                float v0 = ssp_f(acc1[mt][0][r]);
                float v1 = ssp_f(acc1[mt][1][r]);
                float v2 = ssp_f(acc1[mt][2][r]);
                float v3 = ssp_f(acc1[mt][3][r]);
                uint2 u = make_uint2(f2bf2u(v0, v1), f2bf2u(v2, v3));
                *(uint2*)&hid[e * 264 + w * 64 + l15 * 4] = u;
            }
        }

        // ---- issue next tile's dependent meta loads (perm arrived by now)
        int ivn = (ppn < E) ? eidx[eLn] : -1;
        int jvn = eidx[E + eLn];
        float d0n = ew[eLn*3+0], d1n = ew[eLn*3+1], d2n = ew[eLn*3+2];

        __syncthreads();   // barA: hid + runnode/runcomp (+St) ready

        // ---- GEMM2: [64e x 256k(perm)] @ [256k x 64f]  (register B)
        f32x4 acc2[4][4];
#pragma unroll
        for (int mt = 0; mt < 4; ++mt)
#pragma unroll
            for (int nt = 0; nt < 4; ++nt) acc2[mt][nt] = (f32x4){0.f,0.f,0.f,0.f};
#pragma unroll
        for (int kt = 0; kt < 8; ++kt) {
            bf16x8 af[4];
#pragma unroll
            for (int mt = 0; mt < 4; ++mt)
                af[mt] = *(bf16x8*)&hid[(mt * 16 + l15) * 264 + kt * 32 + quad * 8];
#pragma unroll
            for (int nt = 0; nt < 4; ++nt)
#pragma unroll
                for (int mt = 0; mt < 4; ++mt)
                    acc2[mt][nt] = __builtin_amdgcn_mfma_f32_16x16x32_bf16(af[mt], w2f[kt][nt], acc2[mt][nt], 0, 0, 0);
        }
        __syncthreads();   // barB: hid dead; msgT may now overwrite

        // ---- msg epilogue -> msgT[col][e] (wave-private rows; no barrier after)
        float cs[4][4];
#pragma unroll
        for (int mt = 0; mt < 4; ++mt)
#pragma unroll
            for (int r = 0; r < 4; ++r)
                cs[mt][r] = __shfl(c, mt * 16 + quad * 4 + r);
#pragma unroll
        for (int mt = 0; mt < 4; ++mt) {
#pragma unroll
            for (int nt = 0; nt < 4; ++nt) {
                int col = w * 64 + nt * 16 + l15;
                float v0 = (acc2[mt][nt][0] + bias2[nt]) * cs[mt][0] * bf2f(yv[mt][0][nt]);
                float v1 = (acc2[mt][nt][1] + bias2[nt]) * cs[mt][1] * bf2f(yv[mt][1][nt]);
                float v2 = (acc2[mt][nt][2] + bias2[nt]) * cs[mt][2] * bf2f(yv[mt][2][nt]);
                float v3 = (acc2[mt][nt][3] + bias2[nt]) * cs[mt][3] * bf2f(yv[mt][3][nt]);
                uint2 u = make_uint2(f2bf2u(v0, v1), f2bf2u(v2, v3));
                *(uint2*)&msgT[col * 72 + mt * 16 + quad * 4] = u;
            }
        }

        // ---- next tile's c; issue next y_p gather (yv dead after epilogue)
        float dn = sqrtf(d0n*d0n + d1n*d1n + d2n*d2n);
        float cn = (ppn < E && dn <= 2.0f)
                 ? 0.5f * (__cosf(dn * 1.57079632679489662f) + 1.0f) : 0.f;
        issue_yv(y_p, jvn, w, l15, quad, yv);

        // ---- GEMM3: O[feature][run] = msgT @ S^T, then flush per run
        for (int ntg = 0; ntg * 16 < runcnt; ++ntg) {
            if (ntg > 0) {   // rare: >16 runs in a tile
                __syncthreads();
                int e   = tid & 63;
                int rb  = tid >> 6;
                int rid = (int)__popcll(bm & ((1ull << e) - 1ull));
#pragma unroll
                for (int q = 0; q < 4; ++q) {
                    int r = rb + q * 4;
                    St[r * 72 + e] = (rid == ntg * 16 + r) ? (short)0x3F80 : (short)0;
                }
                __syncthreads();
            }
            f32x4 acc3[4];
#pragma unroll
            for (int mt = 0; mt < 4; ++mt) acc3[mt] = (f32x4){0.f,0.f,0.f,0.f};
#pragma unroll
            for (int kt = 0; kt < 2; ++kt) {
                bf16x8 bS = *(bf16x8*)&St[l15 * 72 + kt * 32 + quad * 8];
#pragma unroll
                for (int mt = 0; mt < 4; ++mt) {
                    bf16x8 af = *(bf16x8*)&msgT[(w*64 + mt*16 + l15) * 72 + kt*32 + quad*8];
                    acc3[mt] = __builtin_amdgcn_mfma_f32_16x16x32_bf16(af, bS, acc3[mt], 0, 0, 0);
                }
            }
            int r = ntg * 16 + l15;
            if (r < runcnt) {
                int node = s_runnode[r];
                if (node >= 0) {
                    float* ap = agg + (size_t)node * HF + w * 64 + quad * 4;
                    if (s_runcomp[r]) {
#pragma unroll
                        for (int mt = 0; mt < 4; ++mt) {
                            float4 v = make_float4(acc3[mt][0], acc3[mt][1], acc3[mt][2], acc3[mt][3]);
                            *(float4*)(ap + mt * 16) = v;
                        }
                    } else {
#pragma unroll
                        for (int mt = 0; mt < 4; ++mt)
#pragma unroll
                            for (int g = 0; g < 4; ++g)
                                atomicAdd(ap + mt * 16 + g, acc3[mt][g]);
                    }
                }
            }
        }

        // ---- prefetch next tile's raw ea (a1 regs dead since GEMM1)
        issue_ea(ea, eLn, l15, quad, rp0, rp1, rq0, rq1);

        __syncthreads();   // barEnd: msgT/runnode recycled next iteration

        eL = eLn; iv = ivn; jv = jvn; c = cn;
    }
}

// ---------------------------------------------------------------------------
extern "C" void kernel_launch(void* const* d_in, const int* in_sizes, int n_in,
                              void* d_out, int out_size, void* d_ws, size_t ws_size,
                              hipStream_t stream)
{
    const float* x     = (const float*)d_in[0];
    const int*   eidx  = (const int*)  d_in[1];
    const float* ew    = (const float*)d_in[2];
    const float* ea    = (const float*)d_in[3];
    const float* w1    = (const float*)d_in[4];
    const float* b1    = (const float*)d_in[5];
    const float* w2    = (const float*)d_in[6];
    const float* b2    = (const float*)d_in[7];
    const float* lin1  = (const float*)d_in[8];
    const float* lin2  = (const float*)d_in[9];
    const float* lin2b = (const float*)d_in[10];
    float* out = (float*)d_out;

    const int N = in_sizes[0] / HF;
    const int E = in_sizes[2] / 3;

    const size_t fN = (size_t)N * HF;
    float* agg    = (float*)d_ws;                    // N*256 f32
    short* y_p    = (short*)(agg + fN);              // N*256 bf16 (pi-permuted)
    short* x_bf   = y_p + fN;                        // N*256 bf16
    int*   cnt    = (int*)(x_bf + fN);
    int*   row    = cnt + N;                         // N+1
    int*   cursor = row + (N + 8);
    int*   perm   = cursor + N;
    short* w1p    = (short*)(((uintptr_t)(perm + E) + 255) & ~(uintptr_t)255);
    short* w2p    = w1p + 16384;                     // 32 KB / 128 KB
    short* lin1p  = w2p + 65536;
    short* lin2p  = lin1p + 65536;

    hipMemsetAsync(cnt, 0, (size_t)N * sizeof(int), stream);

    const int nx8   = (int)(fN / 8);
    const int nAgg4 = (int)(fN / 4);
    const int gConv = (nx8 + 255) / 256;
    const int gHist = (E + 255) / 256;
    const int gZero = (nAgg4 + 255) / 256;
    prep_kernel<<<dim3(104 + gConv + gHist + gZero), dim3(256), 0, stream>>>(
        w1, b1, w2, lin1, lin2, w1p, w2p, lin1p, lin2p, x, x_bf, nx8,
        eidx, cnt, E, agg, nAgg4, gConv, gHist);

    const int gNode = (N + 31) / 32;
    gemm_scan_kernel<<<dim3(gNode + 1), dim3(256), 0, stream>>>(
        x_bf, lin1p, y_p, N, cnt, row, cursor, E, gNode);

    const int gScatter = (E + 255) / 256;
    scatter_kernel<<<dim3(gScatter), dim3(256), 0, stream>>>(eidx, cursor, perm, E);

    const int nT = (E + 63) / 64;
    const int gE = nT < 1000 ? nT : 1000;
    edge_mfma<<<dim3(gE), dim3(256), 0, stream>>>(
        ea, eidx, ew, w1p, w2p, b2, y_p, perm, row, agg, E, gE * 64);

    node2_kernel<<<dim3(gNode), dim3(256), 0, stream>>>(
        agg, lin2p, lin2b, x, out, N);
}

// Round 5
// 357.670 us; speedup vs baseline: 1.8299x; 1.8299x over previous
//
#include <hip/hip_runtime.h>
#include <hip/hip_bf16.h>
#include <stdint.h>

#define HF 256   // H == F == 256
#define GG 50    // G

typedef __attribute__((ext_vector_type(8))) short bf16x8;
typedef __attribute__((ext_vector_type(4))) short bf16x4;
typedef __attribute__((ext_vector_type(4))) float f32x4;
typedef float f32x4a __attribute__((ext_vector_type(4), aligned(4)));  // dword-aligned vec4 load

// packed f32x2 -> bf16x2 (v_cvt_pk_bf16_f32 on gfx950), low short = a
__device__ __forceinline__ uint32_t f2bf2u(float a, float b){
    __hip_bfloat162 h = __float22bfloat162_rn(make_float2(a, b));
    union { __hip_bfloat162 h; uint32_t u; } v; v.h = h; return v.u;
}
__device__ __forceinline__ float bf2f(short s){
    union { uint32_t u; float f; } v; v.u = ((uint32_t)(uint16_t)s) << 16;
    return v.f;
}
// shifted softplus: ln(1+e^x) - ln2 (safe for |x| < ~80; GEMM outputs are O(+-6))
__device__ __forceinline__ float ssp_f(float x){
    float e = __builtin_amdgcn_exp2f(x * 1.44269504088896341f);
    return 0.69314718055994531f * __builtin_amdgcn_logf(1.0f + e)
         - 0.69314718055994531f;
}

// ---------------------------------------------------------------------------
// prep_kernel: [pack weights] + [degree histogram]
// B-frag (ntg, kt): lane l holds B[k=kt*32+(l>>4)*8+j][n=ntg*16+(l&15)].
// pi(s) = (s>>6)*64 + (s&3)*16 + ((s&63)>>2)  (hidden-feature storage perm)
// w1p: bias b1 folded in as constant-1 row k=50 (zero-pad region of K=64).
// ---------------------------------------------------------------------------
__device__ __forceinline__ void pack_natural(const float* __restrict__ B,
                                             short* __restrict__ Bp,
                                             int idx, int KT, int kmax)
{
    int lane = idx & 63;
    int kt   = (idx >> 6) & (KT - 1);
    int ntg  = idx >> (6 + (KT == 2 ? 1 : 3));
    int col  = ntg * 16 + (lane & 15);
    int k0   = kt * 32 + (lane >> 4) * 8;
    uint32_t u[4];
#pragma unroll
    for (int jj = 0; jj < 4; ++jj) {
        int ka = k0 + 2*jj, kb = ka + 1;
        float a = (ka < kmax) ? B[(size_t)ka * HF + col] : 0.f;
        float b = (kb < kmax) ? B[(size_t)kb * HF + col] : 0.f;
        u[jj] = f2bf2u(a, b);
    }
    *(uint4*)&Bp[(size_t)idx * 8] = *(uint4*)u;
}

__global__ __launch_bounds__(256)
void prep_kernel(const float* __restrict__ w1, const float* __restrict__ b1,
                 const float* __restrict__ w2,
                 const float* __restrict__ lin1, const float* __restrict__ lin2,
                 short* __restrict__ w1p, short* __restrict__ w2p,
                 short* __restrict__ lin1p, short* __restrict__ lin2p,
                 const int* __restrict__ eidx, int* __restrict__ cnt, int E)
{
    int b = blockIdx.x, tid = threadIdx.x;
    if (b < 8) {                       // w1p with b1 folded at k==GG
        int idx  = b * 256 + tid;
        int lane = idx & 63;
        int kt   = (idx >> 6) & 1;
        int ntg  = idx >> 7;
        int col  = ntg * 16 + (lane & 15);
        int k0   = kt * 32 + (lane >> 4) * 8;
        uint32_t u[4];
#pragma unroll
        for (int jj = 0; jj < 4; ++jj) {
            int ka = k0 + 2*jj, kb = ka + 1;
            float va = (ka < GG) ? w1[(size_t)ka * HF + col]
                                 : ((ka == GG) ? b1[col] : 0.f);
            float vb = (kb < GG) ? w1[(size_t)kb * HF + col]
                                 : ((kb == GG) ? b1[col] : 0.f);
            u[jj] = f2bf2u(va, vb);
        }
        *(uint4*)&w1p[(size_t)idx * 8] = *(uint4*)u;
    } else if (b < 40) {               // w2p: permuted k axis
        int idx = (b - 8) * 256 + tid;
        int lane = idx & 63;
        int kt   = (idx >> 6) & 7;
        int ntg  = idx >> 9;
        int col  = ntg * 16 + (lane & 15);
        int s0   = kt * 32 + (lane >> 4) * 8;
        uint32_t u[4];
#pragma unroll
        for (int jj = 0; jj < 4; ++jj) {
            int sa = s0 + 2*jj, sb = sa + 1;
            int fa = (sa >> 6) * 64 + (sa & 3) * 16 + ((sa & 63) >> 2);
            int fb = (sb >> 6) * 64 + (sb & 3) * 16 + ((sb & 63) >> 2);
            u[jj] = f2bf2u(w2[(size_t)fa * HF + col], w2[(size_t)fb * HF + col]);
        }
        *(uint4*)&w2p[(size_t)idx * 8] = *(uint4*)u;
    } else if (b < 72) {
        pack_natural(lin1, lin1p, (b - 40) * 256 + tid, 8, HF);
    } else if (b < 104) {
        pack_natural(lin2, lin2p, (b - 72) * 256 + tid, 8, HF);
    } else {                           // histogram
        int e = (b - 104) * 256 + tid;
        if (e < E) atomicAdd(&cnt[eidx[e]], 1);
    }
}

// ---------------------------------------------------------------------------
// scan_zero_kernel: block 0 = exclusive scan (serial, latency-bound);
// blocks 1..gZero ride along zeroing agg concurrently on other CUs.
// ---------------------------------------------------------------------------
__global__ __launch_bounds__(256)
void scan_zero_kernel(const int* __restrict__ cnt, int* __restrict__ row,
                      int* __restrict__ cursor, int N, int E,
                      float* __restrict__ agg, int nAgg4)
{
    const int t = threadIdx.x;
    if (blockIdx.x > 0) {              // agg zero (float4 granular)
        int idx = ((int)blockIdx.x - 1) * 256 + t;
        if (idx < nAgg4) ((float4*)agg)[idx] = make_float4(0.f, 0.f, 0.f, 0.f);
        return;
    }
    __shared__ int part[256];
    const int CH = (N + 255) / 256;
    int lo = t * CH;
    int hi = min(lo + CH, N);
    int s = 0;
    for (int n = lo; n < hi; ++n) s += cnt[n];
    part[t] = s;
    __syncthreads();
    for (int off = 1; off < 256; off <<= 1) {
        int v = (t >= off) ? part[t - off] : 0;
        __syncthreads();
        part[t] += v;
        __syncthreads();
    }
    int acc = part[t] - s;   // exclusive
    for (int n = lo; n < hi; ++n) {
        row[n] = acc; cursor[n] = acc;
        acc += cnt[n];
    }
    if (t == 255) row[N] = E;
}

// ---------------------------------------------------------------------------
// mid_kernel: [scatter perm] + [node GEMM1: y_p = bf16(pi-perm) x@lin1]
// M-tile = 64 (157 blocks): fewer lin1p re-fetches than M=32; x read as fp32
// directly (x_bf intermediate eliminated -> saves 15 MB traffic + prep blocks).
// ---------------------------------------------------------------------------
__global__ __launch_bounds__(256)
void mid_kernel(const int* __restrict__ eidx, int* __restrict__ cursor,
                int* __restrict__ perm, int E, int gScatter,
                const float* __restrict__ x, const short* __restrict__ lin1p,
                short* __restrict__ y_p, int N)
{
    const int tid = threadIdx.x;
    if ((int)blockIdx.x < gScatter) {
        int e = blockIdx.x * 256 + tid;
        if (e < E) {
            int pos = atomicAdd(&cursor[eidx[e]], 1);
            perm[pos] = e;
        }
        return;
    }
    const int blk  = blockIdx.x - gScatter;
    const int lane = tid & 63;
    const int w    = tid >> 6;
    const int l15  = lane & 15;
    const int quad = lane >> 4;
    const int row0 = blk * 64;

    f32x4 acc[4][4];
#pragma unroll
    for (int mt = 0; mt < 4; ++mt)
#pragma unroll
        for (int nt = 0; nt < 4; ++nt) acc[mt][nt] = (f32x4){0.f,0.f,0.f,0.f};

#pragma unroll 2
    for (int kt = 0; kt < 8; ++kt) {
        bf16x8 af[4];
#pragma unroll
        for (int mt = 0; mt < 4; ++mt) {
            int r = row0 + mt * 16 + l15;
            int rl = (r < N) ? r : 0;
            const float* ap = x + (size_t)rl * HF + kt * 32 + quad * 8;
            f32x4a p0 = *(const f32x4a*)(ap);
            f32x4a p1 = *(const f32x4a*)(ap + 4);
            union { uint32_t u[4]; bf16x8 v; } c;
            c.u[0] = f2bf2u(p0[0], p0[1]); c.u[1] = f2bf2u(p0[2], p0[3]);
            c.u[2] = f2bf2u(p1[0], p1[1]); c.u[3] = f2bf2u(p1[2], p1[3]);
            af[mt] = c.v;
        }
#pragma unroll
        for (int nt = 0; nt < 4; ++nt) {
            bf16x8 bfr = *(const bf16x8*)&lin1p[(size_t)(((w*4+nt)*8+kt)*64+lane)*8];
#pragma unroll
            for (int mt = 0; mt < 4; ++mt)
                acc[mt][nt] = __builtin_amdgcn_mfma_f32_16x16x32_bf16(af[mt], bfr, acc[mt][nt], 0, 0, 0);
        }
    }
#pragma unroll
    for (int mt = 0; mt < 4; ++mt) {
#pragma unroll
        for (int r = 0; r < 4; ++r) {
            int row = row0 + mt * 16 + quad * 4 + r;
            if (row < N) {
                uint2 u = make_uint2(f2bf2u(acc[mt][0][r], acc[mt][1][r]),
                                     f2bf2u(acc[mt][2][r], acc[mt][3][r]));
                *(uint2*)&y_p[(size_t)row * HF + w * 64 + l15 * 4] = u;
            }
        }
    }
}

// ---------------------------------------------------------------------------
// node2_kernel: out = ssp(agg@lin2 + b) + x   (M-tile 64)
// ---------------------------------------------------------------------------
__global__ __launch_bounds__(256)
void node2_kernel(const float* __restrict__ agg, const short* __restrict__ lin2p,
                  const float* __restrict__ bias, const float* __restrict__ x,
                  float* __restrict__ out, int N)
{
    const int tid  = threadIdx.x;
    const int lane = tid & 63;
    const int w    = tid >> 6;
    const int l15  = lane & 15;
    const int quad = lane >> 4;
    const int row0 = blockIdx.x * 64;

    f32x4 acc[4][4];
#pragma unroll
    for (int mt = 0; mt < 4; ++mt)
#pragma unroll
        for (int nt = 0; nt < 4; ++nt) acc[mt][nt] = (f32x4){0.f,0.f,0.f,0.f};

#pragma unroll 2
    for (int kt = 0; kt < 8; ++kt) {
        bf16x8 af[4];
#pragma unroll
        for (int mt = 0; mt < 4; ++mt) {
            int r = row0 + mt * 16 + l15;
            int rl = (r < N) ? r : 0;
            const float* ap = agg + (size_t)rl * HF + kt * 32 + quad * 8;
            float4 p0 = *(const float4*)(ap);
            float4 p1 = *(const float4*)(ap + 4);
            union { uint32_t u[4]; bf16x8 v; } c;
            c.u[0] = f2bf2u(p0.x, p0.y); c.u[1] = f2bf2u(p0.z, p0.w);
            c.u[2] = f2bf2u(p1.x, p1.y); c.u[3] = f2bf2u(p1.z, p1.w);
            af[mt] = c.v;
        }
#pragma unroll
        for (int nt = 0; nt < 4; ++nt) {
            bf16x8 bfr = *(const bf16x8*)&lin2p[(size_t)(((w*4+nt)*8+kt)*64+lane)*8];
#pragma unroll
            for (int mt = 0; mt < 4; ++mt)
                acc[mt][nt] = __builtin_amdgcn_mfma_f32_16x16x32_bf16(af[mt], bfr, acc[mt][nt], 0, 0, 0);
        }
    }
    float bs[4];
#pragma unroll
    for (int nt = 0; nt < 4; ++nt) bs[nt] = bias[w * 64 + nt * 16 + l15];
#pragma unroll
    for (int mt = 0; mt < 4; ++mt) {
#pragma unroll
        for (int r = 0; r < 4; ++r) {
            int row = row0 + mt * 16 + quad * 4 + r;
            if (row < N) {
#pragma unroll
                for (int nt = 0; nt < 4; ++nt) {
                    int f = w * 64 + nt * 16 + l15;
                    float v = ssp_f(acc[mt][nt][r] + bs[nt]) + x[(size_t)row * HF + f];
                    out[(size_t)row * HF + f] = v;
                }
            }
        }
    }
}

// ---------------------------------------------------------------------------
// edge_mfma: R1 structure (measured best: 158.6 us). Per 64-sorted-edge block,
// 4 waves, wave w owns f-slice [64w,64w+64).
//   GEMM1: hid = ssp(ea @ w1 [+b1 via k=50 one-row]) -> LDS (bf16, pi-perm)
//   GEMM2: W = hid @ w2p; msg = (W+b2)*C*y_p[j] -> msgT[col][e] (stride 72)
//   GEMM3: segment-sum via 0/1 selection matrix (MFMA), per-run f4 stores
// Changes vs R1: St stride 64->72 (kills its 16-way bank conflict; R2-verified
// 5.92M->4.64M), s_setprio(1) around GEMM2 MFMA (T5: streaming blocks at
// different phases = the regime where it measured +4-7%).
// LB(256,4): VGPR 64 + mild spill — measured faster than the no-spill (256,3).
// ---------------------------------------------------------------------------
__global__ __launch_bounds__(256, 4)
void edge_mfma(const float* __restrict__ ea, const int* __restrict__ eidx,
               const float* __restrict__ ew,
               const short* __restrict__ w1p,
               const short* __restrict__ w2p, const float* __restrict__ b2,
               const short* __restrict__ y_p, const int* __restrict__ perm,
               const int* __restrict__ rowp,
               float* __restrict__ agg, int E)
{
    __shared__ short smem[19584];      // 39168 B
    short* ea_b = smem;                // [64][72]   (stage + GEMM1 reads)
    short* hid  = smem;                // [64][264]  (aliases ea_b; barrier-split)
    short* msgT = smem;                // [256][72]  (phase 4+, aliases)
    short* St   = smem + 18432;        // [16][72]
    __shared__ int s_e[64], s_i[64], s_j[64];
    __shared__ float s_c[64];
    __shared__ int s_runnode[64];
    __shared__ unsigned char s_runcomp[64];
    __shared__ unsigned long long s_bmask;
    __shared__ int s_runcnt;

    const int tid  = threadIdx.x;
    const int lane = tid & 63;
    const int w    = tid >> 6;
    const int l15  = lane & 15;
    const int quad = lane >> 4;
    const int e0   = blockIdx.x * 64;

    if (tid < 64) {
        int pp = e0 + tid;
        int e = 0, iv = -1, jv = 0;
        float c = 0.f;
        if (pp < E) {
            e  = perm[pp];
            iv = eidx[e];
            jv = eidx[E + e];
            float d0 = ew[e*3+0], d1 = ew[e*3+1], d2 = ew[e*3+2];
            float d = sqrtf(d0*d0 + d1*d1 + d2*d2);
            c = (d <= 2.0f) ? 0.5f * (__cosf(d * 1.57079632679489662f) + 1.0f) : 0.f;
        }
        s_e[tid] = e; s_i[tid] = iv; s_j[tid] = jv; s_c[tid] = c;
        int ivn = __shfl_down(iv, 1);
        bool flag = (tid == 63) || (iv != ivn);     // run ends at tid
        unsigned long long m = __ballot(flag);
        if (flag) {
            int rid = (int)__popcll(m & ((1ull << tid) - 1ull));
            s_runnode[rid] = iv;
            int comp = 0;
            if (iv >= 0) {
                int lo = rowp[iv], hi = rowp[iv + 1];
                comp = (lo >= e0 && hi <= e0 + 64) ? 1 : 0;
            }
            s_runcomp[rid] = (unsigned char)comp;
        }
        if (tid == 0) { s_bmask = m; s_runcnt = (int)__popcll(m); }
    }
    __syncthreads();

    // stage edge_attr: float2 loads, pk-convert, dword LDS writes
    for (int idx = tid; idx < 64 * 25; idx += 256) {
        int e = idx / 25, q = idx - e * 25;
        const float* sp = ea + (size_t)s_e[e] * GG + q * 2;
        float2 v = *(const float2*)sp;
        *(uint32_t*)&ea_b[e * 72 + q * 2] = f2bf2u(v.x, v.y);
    }
    for (int idx = tid; idx < 64 * 7; idx += 256) {   // k=50 -> 1.0 (bias row), 51..63 -> 0
        int e = idx / 7, q = idx - e * 7;
        *(uint32_t*)&ea_b[e * 72 + 50 + q * 2] = (q == 0) ? 0x00003F80u : 0u;
    }
    __syncthreads();

    // ---- GEMM1: [64e x 64k] @ [64k x 64f-slice]  (bias folded in k=50 row)
    f32x4 acc1[4][4];
#pragma unroll
    for (int mt = 0; mt < 4; ++mt)
#pragma unroll
        for (int nt = 0; nt < 4; ++nt) acc1[mt][nt] = (f32x4){0.f,0.f,0.f,0.f};

#pragma unroll
    for (int kt = 0; kt < 2; ++kt) {
        bf16x8 af[4];
#pragma unroll
        for (int mt = 0; mt < 4; ++mt)
            af[mt] = *(bf16x8*)&ea_b[(mt * 16 + l15) * 72 + kt * 32 + quad * 8];
#pragma unroll
        for (int nt = 0; nt < 4; ++nt) {
            bf16x8 bfr = *(const bf16x8*)&w1p[(size_t)(((w*4+nt)*2+kt)*64+lane)*8];
#pragma unroll
            for (int mt = 0; mt < 4; ++mt)
                acc1[mt][nt] = __builtin_amdgcn_mfma_f32_16x16x32_bf16(af[mt], bfr, acc1[mt][nt], 0, 0, 0);
        }
    }
    __syncthreads();   // ea_b dead everywhere; hid (aliased at base) may be written

    // ssp -> hid (bf16, col' = w*64 + l15*4 + nt)
#pragma unroll
    for (int mt = 0; mt < 4; ++mt) {
#pragma unroll
        for (int r = 0; r < 4; ++r) {
            int e = mt * 16 + quad * 4 + r;
            float v0 = ssp_f(acc1[mt][0][r]);
            float v1 = ssp_f(acc1[mt][1][r]);
            float v2 = ssp_f(acc1[mt][2][r]);
            float v3 = ssp_f(acc1[mt][3][r]);
            uint2 u = make_uint2(f2bf2u(v0, v1), f2bf2u(v2, v3));
            *(uint2*)&hid[e * 264 + w * 64 + l15 * 4] = u;
        }
    }
    __syncthreads();

    // ---- prefetch y_p rows (overlaps GEMM2 MFMA latency)
    bf16x4 yv[4][4];
#pragma unroll
    for (int mt = 0; mt < 4; ++mt)
#pragma unroll
        for (int r = 0; r < 4; ++r) {
            int e = mt * 16 + quad * 4 + r;
            yv[mt][r] = *(const bf16x4*)&y_p[(size_t)s_j[e] * HF + w * 64 + l15 * 4];
        }

    // ---- GEMM2: [64e x 256k(perm)] @ [256k x 64f-slice]
    f32x4 acc2[4][4];
#pragma unroll
    for (int mt = 0; mt < 4; ++mt)
#pragma unroll
        for (int nt = 0; nt < 4; ++nt) acc2[mt][nt] = (f32x4){0.f,0.f,0.f,0.f};

    __builtin_amdgcn_s_setprio(1);
#pragma unroll 2
    for (int kt = 0; kt < 8; ++kt) {
        bf16x8 af[4];
#pragma unroll
        for (int mt = 0; mt < 4; ++mt)
            af[mt] = *(bf16x8*)&hid[(mt * 16 + l15) * 264 + kt * 32 + quad * 8];
#pragma unroll
        for (int nt = 0; nt < 4; ++nt) {
            bf16x8 bfr = *(const bf16x8*)&w2p[(size_t)(((w*4+nt)*8+kt)*64+lane)*8];
#pragma unroll
            for (int mt = 0; mt < 4; ++mt)
                acc2[mt][nt] = __builtin_amdgcn_mfma_f32_16x16x32_bf16(af[mt], bfr, acc2[mt][nt], 0, 0, 0);
        }
    }
    __builtin_amdgcn_s_setprio(0);
    __syncthreads();   // hid dead; msgT/St may now overwrite

    // ---- msg epilogue -> msgT[col][e] (stride 72: 16B-aligned rows)
    float bias2[4];
#pragma unroll
    for (int nt = 0; nt < 4; ++nt) bias2[nt] = b2[w * 64 + nt * 16 + l15];
    float cs[4][4];
#pragma unroll
    for (int mt = 0; mt < 4; ++mt)
#pragma unroll
        for (int r = 0; r < 4; ++r)
            cs[mt][r] = s_c[mt * 16 + quad * 4 + r];
#pragma unroll
    for (int mt = 0; mt < 4; ++mt) {
#pragma unroll
        for (int nt = 0; nt < 4; ++nt) {
            int col = w * 64 + nt * 16 + l15;
            float v0 = (acc2[mt][nt][0] + bias2[nt]) * cs[mt][0] * bf2f(yv[mt][0][nt]);
            float v1 = (acc2[mt][nt][1] + bias2[nt]) * cs[mt][1] * bf2f(yv[mt][1][nt]);
            float v2 = (acc2[mt][nt][2] + bias2[nt]) * cs[mt][2] * bf2f(yv[mt][2][nt]);
            float v3 = (acc2[mt][nt][3] + bias2[nt]) * cs[mt][3] * bf2f(yv[mt][3][nt]);
            uint2 u = make_uint2(f2bf2u(v0, v1), f2bf2u(v2, v3));
            *(uint2*)&msgT[col * 72 + mt * 16 + quad * 4] = u;
        }
    }
    // build S^T[run-local][edge] for run group 0 (stride 72: conflict-free)
    {
        unsigned long long bm = s_bmask;
        int e   = tid & 63;
        int rb  = tid >> 6;
        int rid = (int)__popcll(bm & ((1ull << e) - 1ull));
#pragma unroll
        for (int q = 0; q < 4; ++q) {
            int r = rb + q * 4;
            St[r * 72 + e] = (rid == r) ? (short)0x3F80 : (short)0;
        }
    }
    __syncthreads();

    // ---- GEMM3: O[feature][run] = msgT @ S^T, then flush per run
    const int runcnt = s_runcnt;
    for (int ntg = 0; ntg * 16 < runcnt; ++ntg) {
        if (ntg > 0) {   // rare: >16 runs in a tile
            __syncthreads();
            unsigned long long bm = s_bmask;
            int e   = tid & 63;
            int rb  = tid >> 6;
            int rid = (int)__popcll(bm & ((1ull << e) - 1ull));
#pragma unroll
            for (int q = 0; q < 4; ++q) {
                int r = rb + q * 4;
                St[r * 72 + e] = (rid == ntg * 16 + r) ? (short)0x3F80 : (short)0;
            }
            __syncthreads();
        }
        f32x4 acc3[4];
#pragma unroll
        for (int mt = 0; mt < 4; ++mt) acc3[mt] = (f32x4){0.f,0.f,0.f,0.f};
#pragma unroll
        for (int kt = 0; kt < 2; ++kt) {
            bf16x8 bS = *(bf16x8*)&St[l15 * 72 + kt * 32 + quad * 8];
#pragma unroll
            for (int mt = 0; mt < 4; ++mt) {
                bf16x8 af = *(bf16x8*)&msgT[(w*64 + mt*16 + l15) * 72 + kt*32 + quad*8];
                acc3[mt] = __builtin_amdgcn_mfma_f32_16x16x32_bf16(af, bS, acc3[mt], 0, 0, 0);
            }
        }
        // lane owns run r = ntg*16 + l15; features f = w*64 + mt*16 + quad*4 + g
        int r = ntg * 16 + l15;
        if (r < runcnt) {
            int node = s_runnode[r];
            if (node >= 0) {
                float* ap = agg + (size_t)node * HF + w * 64 + quad * 4;
                if (s_runcomp[r]) {
#pragma unroll
                    for (int mt = 0; mt < 4; ++mt) {
                        float4 v = make_float4(acc3[mt][0], acc3[mt][1], acc3[mt][2], acc3[mt][3]);
                        *(float4*)(ap + mt * 16) = v;
                    }
                } else {
#pragma unroll
                    for (int mt = 0; mt < 4; ++mt)
#pragma unroll
                        for (int g = 0; g < 4; ++g)
                            atomicAdd(ap + mt * 16 + g, acc3[mt][g]);
                }
            }
        }
    }
}

// ---------------------------------------------------------------------------
extern "C" void kernel_launch(void* const* d_in, const int* in_sizes, int n_in,
                              void* d_out, int out_size, void* d_ws, size_t ws_size,
                              hipStream_t stream)
{
    const float* x     = (const float*)d_in[0];
    const int*   eidx  = (const int*)  d_in[1];
    const float* ew    = (const float*)d_in[2];
    const float* ea    = (const float*)d_in[3];
    const float* w1    = (const float*)d_in[4];
    const float* b1    = (const float*)d_in[5];
    const float* w2    = (const float*)d_in[6];
    const float* b2    = (const float*)d_in[7];
    const float* lin1  = (const float*)d_in[8];
    const float* lin2  = (const float*)d_in[9];
    const float* lin2b = (const float*)d_in[10];
    float* out = (float*)d_out;

    const int N = in_sizes[0] / HF;
    const int E = in_sizes[2] / 3;

    const size_t fN = (size_t)N * HF;
    float* agg    = (float*)d_ws;                    // N*256 f32
    short* y_p    = (short*)(agg + fN);              // N*256 bf16 (pi-permuted)
    int*   cnt    = (int*)(y_p + fN);
    int*   row    = cnt + N;                         // N+1
    int*   cursor = row + (N + 8);
    int*   perm   = cursor + N;
    short* w1p    = (short*)(((uintptr_t)(perm + E) + 255) & ~(uintptr_t)255);
    short* w2p    = w1p + 16384;                     // 32 KB / 128 KB
    short* lin1p  = w2p + 65536;
    short* lin2p  = lin1p + 65536;

    hipMemsetAsync(cnt, 0, (size_t)N * sizeof(int), stream);

    const int nAgg4 = (int)(fN / 4);
    const int gHist = (E + 255) / 256;
    const int gZero = (nAgg4 + 255) / 256;

    prep_kernel<<<dim3(104 + gHist), dim3(256), 0, stream>>>(
        w1, b1, w2, lin1, lin2, w1p, w2p, lin1p, lin2p, eidx, cnt, E);

    scan_zero_kernel<<<dim3(1 + gZero), dim3(256), 0, stream>>>(
        cnt, row, cursor, N, E, agg, nAgg4);

    const int gScatter = (E + 255) / 256;
    const int gNode    = (N + 63) / 64;
    mid_kernel<<<dim3(gScatter + gNode), dim3(256), 0, stream>>>(
        eidx, cursor, perm, E, gScatter, x, lin1p, y_p, N);

    edge_mfma<<<dim3((E + 63) / 64), dim3(256), 0, stream>>>(
        ea, eidx, ew, w1p, w2p, b2, y_p, perm, row, agg, E);

    node2_kernel<<<dim3(gNode), dim3(256), 0, stream>>>(
        agg, lin2p, lin2b, x, out, N);
}

// Round 6
// 318.935 us; speedup vs baseline: 2.0522x; 1.1215x over previous
//
#include <hip/hip_runtime.h>
#include <hip/hip_bf16.h>
#include <stdint.h>

#define HF 256   // H == F == 256
#define GG 50    // G

typedef __attribute__((ext_vector_type(8))) short bf16x8;
typedef __attribute__((ext_vector_type(4))) short bf16x4;
typedef __attribute__((ext_vector_type(4))) float f32x4;

// packed f32x2 -> bf16x2 (v_cvt_pk_bf16_f32 on gfx950), low short = a
__device__ __forceinline__ uint32_t f2bf2u(float a, float b){
    __hip_bfloat162 h = __float22bfloat162_rn(make_float2(a, b));
    union { __hip_bfloat162 h; uint32_t u; } v; v.h = h; return v.u;
}
__device__ __forceinline__ float bf2f(short s){
    union { uint32_t u; float f; } v; v.u = ((uint32_t)(uint16_t)s) << 16;
    return v.f;
}
// shifted softplus: ln(1+e^x) - ln2 (safe for |x| < ~80; GEMM outputs are O(+-6))
__device__ __forceinline__ float ssp_f(float x){
    float e = __builtin_amdgcn_exp2f(x * 1.44269504088896341f);
    return 0.69314718055994531f * __builtin_amdgcn_logf(1.0f + e)
         - 0.69314718055994531f;
}

// ---------------------------------------------------------------------------
// prep_kernel: [pack weights] + [x fp32->bf16] + [degree histogram] + [agg=0]
// (R0 organization: zero + conv + hist all concurrent in one launch)
// B-frag (ntg, kt): lane l holds B[k=kt*32+(l>>4)*8+j][n=ntg*16+(l&15)].
// pi(s) = (s>>6)*64 + (s&3)*16 + ((s&63)>>2)  (hidden-feature storage perm)
// w1p: bias b1 folded in as constant-1 row k=50 (zero-pad region of K=64).
// ---------------------------------------------------------------------------
__device__ __forceinline__ void pack_natural(const float* __restrict__ B,
                                             short* __restrict__ Bp,
                                             int idx, int KT, int kmax)
{
    int lane = idx & 63;
    int kt   = (idx >> 6) & (KT - 1);
    int ntg  = idx >> (6 + (KT == 2 ? 1 : 3));
    int col  = ntg * 16 + (lane & 15);
    int k0   = kt * 32 + (lane >> 4) * 8;
    uint32_t u[4];
#pragma unroll
    for (int jj = 0; jj < 4; ++jj) {
        int ka = k0 + 2*jj, kb = ka + 1;
        float a = (ka < kmax) ? B[(size_t)ka * HF + col] : 0.f;
        float b = (kb < kmax) ? B[(size_t)kb * HF + col] : 0.f;
        u[jj] = f2bf2u(a, b);
    }
    *(uint4*)&Bp[(size_t)idx * 8] = *(uint4*)u;
}

__global__ __launch_bounds__(256)
void prep_kernel(const float* __restrict__ w1, const float* __restrict__ b1,
                 const float* __restrict__ w2,
                 const float* __restrict__ lin1, const float* __restrict__ lin2,
                 short* __restrict__ w1p, short* __restrict__ w2p,
                 short* __restrict__ lin1p, short* __restrict__ lin2p,
                 const float* __restrict__ x, short* __restrict__ x_bf, int nx8,
                 const int* __restrict__ eidx, int* __restrict__ cnt, int E,
                 float* __restrict__ agg, int nAgg4, int gConv, int gHist)
{
    int b = blockIdx.x, tid = threadIdx.x;
    if (b < 8) {                       // w1p with b1 folded at k==GG
        int idx  = b * 256 + tid;
        int lane = idx & 63;
        int kt   = (idx >> 6) & 1;
        int ntg  = idx >> 7;
        int col  = ntg * 16 + (lane & 15);
        int k0   = kt * 32 + (lane >> 4) * 8;
        uint32_t u[4];
#pragma unroll
        for (int jj = 0; jj < 4; ++jj) {
            int ka = k0 + 2*jj, kb = ka + 1;
            float va = (ka < GG) ? w1[(size_t)ka * HF + col]
                                 : ((ka == GG) ? b1[col] : 0.f);
            float vb = (kb < GG) ? w1[(size_t)kb * HF + col]
                                 : ((kb == GG) ? b1[col] : 0.f);
            u[jj] = f2bf2u(va, vb);
        }
        *(uint4*)&w1p[(size_t)idx * 8] = *(uint4*)u;
    } else if (b < 40) {               // w2p: permuted k axis
        int idx = (b - 8) * 256 + tid;
        int lane = idx & 63;
        int kt   = (idx >> 6) & 7;
        int ntg  = idx >> 9;
        int col  = ntg * 16 + (lane & 15);
        int s0   = kt * 32 + (lane >> 4) * 8;
        uint32_t u[4];
#pragma unroll
        for (int jj = 0; jj < 4; ++jj) {
            int sa = s0 + 2*jj, sb = sa + 1;
            int fa = (sa >> 6) * 64 + (sa & 3) * 16 + ((sa & 63) >> 2);
            int fb = (sb >> 6) * 64 + (sb & 3) * 16 + ((sb & 63) >> 2);
            u[jj] = f2bf2u(w2[(size_t)fa * HF + col], w2[(size_t)fb * HF + col]);
        }
        *(uint4*)&w2p[(size_t)idx * 8] = *(uint4*)u;
    } else if (b < 72) {
        pack_natural(lin1, lin1p, (b - 40) * 256 + tid, 8, HF);
    } else if (b < 104) {
        pack_natural(lin2, lin2p, (b - 72) * 256 + tid, 8, HF);
    } else if (b < 104 + gConv) {      // x -> bf16, 8 elems/thread
        int idx = (b - 104) * 256 + tid;
        if (idx < nx8) {
            const float* xp = x + (size_t)idx * 8;
            float4 p0 = *(const float4*)(xp);
            float4 p1 = *(const float4*)(xp + 4);
            uint32_t u[4] = { f2bf2u(p0.x, p0.y), f2bf2u(p0.z, p0.w),
                              f2bf2u(p1.x, p1.y), f2bf2u(p1.z, p1.w) };
            *(uint4*)&x_bf[(size_t)idx * 8] = *(uint4*)u;
        }
    } else if (b < 104 + gConv + gHist) {   // histogram
        int e = (b - 104 - gConv) * 256 + tid;
        if (e < E) atomicAdd(&cnt[eidx[e]], 1);
    } else {                           // agg zero (float4 granular)
        int idx = (b - 104 - gConv - gHist) * 256 + tid;
        if (idx < nAgg4) ((float4*)agg)[idx] = make_float4(0.f, 0.f, 0.f, 0.f);
    }
}

// ---------------------------------------------------------------------------
// scan_kernel: exclusive scan over cnt -> row/cursor (1 block, LDS scan)
// ---------------------------------------------------------------------------
__global__ __launch_bounds__(256)
void scan_kernel(const int* __restrict__ cnt, int* __restrict__ row,
                 int* __restrict__ cursor, int N, int E)
{
    __shared__ int part[256];
    const int t = threadIdx.x;
    const int CH = (N + 255) / 256;
    int lo = t * CH;
    int hi = min(lo + CH, N);
    int s = 0;
    for (int n = lo; n < hi; ++n) s += cnt[n];
    part[t] = s;
    __syncthreads();
    for (int off = 1; off < 256; off <<= 1) {
        int v = (t >= off) ? part[t - off] : 0;
        __syncthreads();
        part[t] += v;
        __syncthreads();
    }
    int acc = part[t] - s;   // exclusive
    for (int n = lo; n < hi; ++n) {
        row[n] = acc; cursor[n] = acc;
        acc += cnt[n];
    }
    if (t == 255) row[N] = E;
}

// ---------------------------------------------------------------------------
// mid_kernel: [scatter perm] + [node GEMM1: y_p = bf16(pi-perm) x@lin1]
// M-tile 64 (R0 measured-best organization; x_bf bf16 reads)
// ---------------------------------------------------------------------------
__global__ __launch_bounds__(256)
void mid_kernel(const int* __restrict__ eidx, int* __restrict__ cursor,
                int* __restrict__ perm, int E, int gScatter,
                const short* __restrict__ x_bf, const short* __restrict__ lin1p,
                short* __restrict__ y_p, int N)
{
    const int tid = threadIdx.x;
    if ((int)blockIdx.x < gScatter) {
        int e = blockIdx.x * 256 + tid;
        if (e < E) {
            int pos = atomicAdd(&cursor[eidx[e]], 1);
            perm[pos] = e;
        }
        return;
    }
    const int blk  = blockIdx.x - gScatter;
    const int lane = tid & 63;
    const int w    = tid >> 6;
    const int l15  = lane & 15;
    const int quad = lane >> 4;
    const int row0 = blk * 64;

    f32x4 acc[4][4];
#pragma unroll
    for (int mt = 0; mt < 4; ++mt)
#pragma unroll
        for (int nt = 0; nt < 4; ++nt) acc[mt][nt] = (f32x4){0.f,0.f,0.f,0.f};

#pragma unroll 2
    for (int kt = 0; kt < 8; ++kt) {
        bf16x8 af[4];
#pragma unroll
        for (int mt = 0; mt < 4; ++mt) {
            int r = row0 + mt * 16 + l15;
            int rl = (r < N) ? r : 0;
            af[mt] = *(const bf16x8*)&x_bf[(size_t)rl * HF + kt * 32 + quad * 8];
        }
#pragma unroll
        for (int nt = 0; nt < 4; ++nt) {
            bf16x8 bfr = *(const bf16x8*)&lin1p[(size_t)(((w*4+nt)*8+kt)*64+lane)*8];
#pragma unroll
            for (int mt = 0; mt < 4; ++mt)
                acc[mt][nt] = __builtin_amdgcn_mfma_f32_16x16x32_bf16(af[mt], bfr, acc[mt][nt], 0, 0, 0);
        }
    }
#pragma unroll
    for (int mt = 0; mt < 4; ++mt) {
#pragma unroll
        for (int r = 0; r < 4; ++r) {
            int row = row0 + mt * 16 + quad * 4 + r;
            if (row < N) {
                uint2 u = make_uint2(f2bf2u(acc[mt][0][r], acc[mt][1][r]),
                                     f2bf2u(acc[mt][2][r], acc[mt][3][r]));
                *(uint2*)&y_p[(size_t)row * HF + w * 64 + l15 * 4] = u;
            }
        }
    }
}

// ---------------------------------------------------------------------------
// node2_kernel: out = ssp(agg@lin2 + b) + x   (M-tile 64)
// ---------------------------------------------------------------------------
__global__ __launch_bounds__(256)
void node2_kernel(const float* __restrict__ agg, const short* __restrict__ lin2p,
                  const float* __restrict__ bias, const float* __restrict__ x,
                  float* __restrict__ out, int N)
{
    const int tid  = threadIdx.x;
    const int lane = tid & 63;
    const int w    = tid >> 6;
    const int l15  = lane & 15;
    const int quad = lane >> 4;
    const int row0 = blockIdx.x * 64;

    f32x4 acc[4][4];
#pragma unroll
    for (int mt = 0; mt < 4; ++mt)
#pragma unroll
        for (int nt = 0; nt < 4; ++nt) acc[mt][nt] = (f32x4){0.f,0.f,0.f,0.f};

#pragma unroll 2
    for (int kt = 0; kt < 8; ++kt) {
        bf16x8 af[4];
#pragma unroll
        for (int mt = 0; mt < 4; ++mt) {
            int r = row0 + mt * 16 + l15;
            int rl = (r < N) ? r : 0;
            const float* ap = agg + (size_t)rl * HF + kt * 32 + quad * 8;
            float4 p0 = *(const float4*)(ap);
            float4 p1 = *(const float4*)(ap + 4);
            union { uint32_t u[4]; bf16x8 v; } c;
            c.u[0] = f2bf2u(p0.x, p0.y); c.u[1] = f2bf2u(p0.z, p0.w);
            c.u[2] = f2bf2u(p1.x, p1.y); c.u[3] = f2bf2u(p1.z, p1.w);
            af[mt] = c.v;
        }
#pragma unroll
        for (int nt = 0; nt < 4; ++nt) {
            bf16x8 bfr = *(const bf16x8*)&lin2p[(size_t)(((w*4+nt)*8+kt)*64+lane)*8];
#pragma unroll
            for (int mt = 0; mt < 4; ++mt)
                acc[mt][nt] = __builtin_amdgcn_mfma_f32_16x16x32_bf16(af[mt], bfr, acc[mt][nt], 0, 0, 0);
        }
    }
    float bs[4];
#pragma unroll
    for (int nt = 0; nt < 4; ++nt) bs[nt] = bias[w * 64 + nt * 16 + l15];
#pragma unroll
    for (int mt = 0; mt < 4; ++mt) {
#pragma unroll
        for (int r = 0; r < 4; ++r) {
            int row = row0 + mt * 16 + quad * 4 + r;
            if (row < N) {
#pragma unroll
                for (int nt = 0; nt < 4; ++nt) {
                    int f = w * 64 + nt * 16 + l15;
                    float v = ssp_f(acc[mt][nt][r] + bs[nt]) + x[(size_t)row * HF + f];
                    out[(size_t)row * HF + f] = v;
                }
            }
        }
    }
}

// ---------------------------------------------------------------------------
// edge_mfma: R1/R5 structure with a VGPR diet to hit the no-spill AND
// 4-blocks/CU quadrant. LB(256,4) caps unified regs at 128/wave (m69:
// waves halve at 64/128/256); acc takes 64 AGPR, so arch VGPRs cap at 64.
// The ~140 MB/dispatch scratch traffic (45% of edge HBM) came from regs
// live across GEMM2 beyond that cap. Diet:
//   - GEMM2 kt-loop unroll 1 (halves in-flight af/w2p fragments)
//   - yv gather issued AFTER GEMM2, before its barrier (latency hides in
//     barrier drain + TLP; frees 16 VGPRs across the peak region)
//   - bias2 loaded after GEMM2
// ---------------------------------------------------------------------------
__global__ __launch_bounds__(256, 4)
void edge_mfma(const float* __restrict__ ea, const int* __restrict__ eidx,
               const float* __restrict__ ew,
               const short* __restrict__ w1p,
               const short* __restrict__ w2p, const float* __restrict__ b2,
               const short* __restrict__ y_p, const int* __restrict__ perm,
               const int* __restrict__ rowp,
               float* __restrict__ agg, int E)
{
    __shared__ short smem[19584];      // 39168 B
    short* ea_b = smem;                // [64][72]   (stage + GEMM1 reads)
    short* hid  = smem;                // [64][264]  (aliases ea_b; barrier-split)
    short* msgT = smem;                // [256][72]  (phase 4+, aliases)
    short* St   = smem + 18432;        // [16][72]
    __shared__ int s_e[64], s_i[64], s_j[64];
    __shared__ float s_c[64];
    __shared__ int s_runnode[64];
    __shared__ unsigned char s_runcomp[64];
    __shared__ unsigned long long s_bmask;
    __shared__ int s_runcnt;

    const int tid  = threadIdx.x;
    const int lane = tid & 63;
    const int w    = tid >> 6;
    const int l15  = lane & 15;
    const int quad = lane >> 4;
    const int e0   = blockIdx.x * 64;

    if (tid < 64) {
        int pp = e0 + tid;
        int e = 0, iv = -1, jv = 0;
        float c = 0.f;
        if (pp < E) {
            e  = perm[pp];
            iv = eidx[e];
            jv = eidx[E + e];
            float d0 = ew[e*3+0], d1 = ew[e*3+1], d2 = ew[e*3+2];
            float d = sqrtf(d0*d0 + d1*d1 + d2*d2);
            c = (d <= 2.0f) ? 0.5f * (__cosf(d * 1.57079632679489662f) + 1.0f) : 0.f;
        }
        s_e[tid] = e; s_i[tid] = iv; s_j[tid] = jv; s_c[tid] = c;
        int ivn = __shfl_down(iv, 1);
        bool flag = (tid == 63) || (iv != ivn);     // run ends at tid
        unsigned long long m = __ballot(flag);
        if (flag) {
            int rid = (int)__popcll(m & ((1ull << tid) - 1ull));
            s_runnode[rid] = iv;
            int comp = 0;
            if (iv >= 0) {
                int lo = rowp[iv], hi = rowp[iv + 1];
                comp = (lo >= e0 && hi <= e0 + 64) ? 1 : 0;
            }
            s_runcomp[rid] = (unsigned char)comp;
        }
        if (tid == 0) { s_bmask = m; s_runcnt = (int)__popcll(m); }
    }
    __syncthreads();

    // stage edge_attr: float2 loads, pk-convert, dword LDS writes
    for (int idx = tid; idx < 64 * 25; idx += 256) {
        int e = idx / 25, q = idx - e * 25;
        const float* sp = ea + (size_t)s_e[e] * GG + q * 2;
        float2 v = *(const float2*)sp;
        *(uint32_t*)&ea_b[e * 72 + q * 2] = f2bf2u(v.x, v.y);
    }
    for (int idx = tid; idx < 64 * 7; idx += 256) {   // k=50 -> 1.0 (bias row), 51..63 -> 0
        int e = idx / 7, q = idx - e * 7;
        *(uint32_t*)&ea_b[e * 72 + 50 + q * 2] = (q == 0) ? 0x00003F80u : 0u;
    }
    __syncthreads();

    // ---- GEMM1: [64e x 64k] @ [64k x 64f-slice]  (bias folded in k=50 row)
    f32x4 acc1[4][4];
#pragma unroll
    for (int mt = 0; mt < 4; ++mt)
#pragma unroll
        for (int nt = 0; nt < 4; ++nt) acc1[mt][nt] = (f32x4){0.f,0.f,0.f,0.f};

#pragma unroll
    for (int kt = 0; kt < 2; ++kt) {
        bf16x8 af[4];
#pragma unroll
        for (int mt = 0; mt < 4; ++mt)
            af[mt] = *(bf16x8*)&ea_b[(mt * 16 + l15) * 72 + kt * 32 + quad * 8];
#pragma unroll
        for (int nt = 0; nt < 4; ++nt) {
            bf16x8 bfr = *(const bf16x8*)&w1p[(size_t)(((w*4+nt)*2+kt)*64+lane)*8];
#pragma unroll
            for (int mt = 0; mt < 4; ++mt)
                acc1[mt][nt] = __builtin_amdgcn_mfma_f32_16x16x32_bf16(af[mt], bfr, acc1[mt][nt], 0, 0, 0);
        }
    }
    __syncthreads();   // ea_b dead everywhere; hid (aliased at base) may be written

    // ssp -> hid (bf16, col' = w*64 + l15*4 + nt)
#pragma unroll
    for (int mt = 0; mt < 4; ++mt) {
#pragma unroll
        for (int r = 0; r < 4; ++r) {
            int e = mt * 16 + quad * 4 + r;
            float v0 = ssp_f(acc1[mt][0][r]);
            float v1 = ssp_f(acc1[mt][1][r]);
            float v2 = ssp_f(acc1[mt][2][r]);
            float v3 = ssp_f(acc1[mt][3][r]);
            uint2 u = make_uint2(f2bf2u(v0, v1), f2bf2u(v2, v3));
            *(uint2*)&hid[e * 264 + w * 64 + l15 * 4] = u;
        }
    }
    __syncthreads();

    // ---- GEMM2: [64e x 256k(perm)] @ [256k x 64f-slice]
    f32x4 acc2[4][4];
#pragma unroll
    for (int mt = 0; mt < 4; ++mt)
#pragma unroll
        for (int nt = 0; nt < 4; ++nt) acc2[mt][nt] = (f32x4){0.f,0.f,0.f,0.f};

    __builtin_amdgcn_s_setprio(1);
#pragma unroll 1
    for (int kt = 0; kt < 8; ++kt) {
        bf16x8 af[4];
#pragma unroll
        for (int mt = 0; mt < 4; ++mt)
            af[mt] = *(bf16x8*)&hid[(mt * 16 + l15) * 264 + kt * 32 + quad * 8];
#pragma unroll
        for (int nt = 0; nt < 4; ++nt) {
            bf16x8 bfr = *(const bf16x8*)&w2p[(size_t)(((w*4+nt)*8+kt)*64+lane)*8];
#pragma unroll
            for (int mt = 0; mt < 4; ++mt)
                acc2[mt][nt] = __builtin_amdgcn_mfma_f32_16x16x32_bf16(af[mt], bfr, acc2[mt][nt], 0, 0, 0);
        }
    }
    __builtin_amdgcn_s_setprio(0);

    // ---- y_p gather issued here: af/w2p regs dead, loads drain across the
    // barrier; consumed immediately after in the epilogue.
    bf16x4 yv[4][4];
#pragma unroll
    for (int mt = 0; mt < 4; ++mt)
#pragma unroll
        for (int r = 0; r < 4; ++r) {
            int e = mt * 16 + quad * 4 + r;
            yv[mt][r] = *(const bf16x4*)&y_p[(size_t)s_j[e] * HF + w * 64 + l15 * 4];
        }
    float bias2[4];
#pragma unroll
    for (int nt = 0; nt < 4; ++nt) bias2[nt] = b2[w * 64 + nt * 16 + l15];

    __syncthreads();   // hid dead; msgT/St may now overwrite

    // ---- msg epilogue -> msgT[col][e] (stride 72: 16B-aligned rows)
    float cs[4][4];
#pragma unroll
    for (int mt = 0; mt < 4; ++mt)
#pragma unroll
        for (int r = 0; r < 4; ++r)
            cs[mt][r] = s_c[mt * 16 + quad * 4 + r];
#pragma unroll
    for (int mt = 0; mt < 4; ++mt) {
#pragma unroll
        for (int nt = 0; nt < 4; ++nt) {
            int col = w * 64 + nt * 16 + l15;
            float v0 = (acc2[mt][nt][0] + bias2[nt]) * cs[mt][0] * bf2f(yv[mt][0][nt]);
            float v1 = (acc2[mt][nt][1] + bias2[nt]) * cs[mt][1] * bf2f(yv[mt][1][nt]);
            float v2 = (acc2[mt][nt][2] + bias2[nt]) * cs[mt][2] * bf2f(yv[mt][2][nt]);
            float v3 = (acc2[mt][nt][3] + bias2[nt]) * cs[mt][3] * bf2f(yv[mt][3][nt]);
            uint2 u = make_uint2(f2bf2u(v0, v1), f2bf2u(v2, v3));
            *(uint2*)&msgT[col * 72 + mt * 16 + quad * 4] = u;
        }
    }
    // build S^T[run-local][edge] for run group 0 (stride 72: conflict-free)
    {
        unsigned long long bm = s_bmask;
        int e   = tid & 63;
        int rb  = tid >> 6;
        int rid = (int)__popcll(bm & ((1ull << e) - 1ull));
#pragma unroll
        for (int q = 0; q < 4; ++q) {
            int r = rb + q * 4;
            St[r * 72 + e] = (rid == r) ? (short)0x3F80 : (short)0;
        }
    }
    __syncthreads();

    // ---- GEMM3: O[feature][run] = msgT @ S^T, then flush per run
    const int runcnt = s_runcnt;
    for (int ntg = 0; ntg * 16 < runcnt; ++ntg) {
        if (ntg > 0) {   // rare: >16 runs in a tile
            __syncthreads();
            unsigned long long bm = s_bmask;
            int e   = tid & 63;
            int rb  = tid >> 6;
            int rid = (int)__popcll(bm & ((1ull << e) - 1ull));
#pragma unroll
            for (int q = 0; q < 4; ++q) {
                int r = rb + q * 4;
                St[r * 72 + e] = (rid == ntg * 16 + r) ? (short)0x3F80 : (short)0;
            }
            __syncthreads();
        }
        f32x4 acc3[4];
#pragma unroll
        for (int mt = 0; mt < 4; ++mt) acc3[mt] = (f32x4){0.f,0.f,0.f,0.f};
#pragma unroll
        for (int kt = 0; kt < 2; ++kt) {
            bf16x8 bS = *(bf16x8*)&St[l15 * 72 + kt * 32 + quad * 8];
#pragma unroll
            for (int mt = 0; mt < 4; ++mt) {
                bf16x8 af = *(bf16x8*)&msgT[(w*64 + mt*16 + l15) * 72 + kt*32 + quad*8];
                acc3[mt] = __builtin_amdgcn_mfma_f32_16x16x32_bf16(af, bS, acc3[mt], 0, 0, 0);
            }
        }
        // lane owns run r = ntg*16 + l15; features f = w*64 + mt*16 + quad*4 + g
        int r = ntg * 16 + l15;
        if (r < runcnt) {
            int node = s_runnode[r];
            if (node >= 0) {
                float* ap = agg + (size_t)node * HF + w * 64 + quad * 4;
                if (s_runcomp[r]) {
#pragma unroll
                    for (int mt = 0; mt < 4; ++mt) {
                        float4 v = make_float4(acc3[mt][0], acc3[mt][1], acc3[mt][2], acc3[mt][3]);
                        *(float4*)(ap + mt * 16) = v;
                    }
                } else {
#pragma unroll
                    for (int mt = 0; mt < 4; ++mt)
#pragma unroll
                        for (int g = 0; g < 4; ++g)
                            atomicAdd(ap + mt * 16 + g, acc3[mt][g]);
                }
            }
        }
    }
}

// ---------------------------------------------------------------------------
extern "C" void kernel_launch(void* const* d_in, const int* in_sizes, int n_in,
                              void* d_out, int out_size, void* d_ws, size_t ws_size,
                              hipStream_t stream)
{
    const float* x     = (const float*)d_in[0];
    const int*   eidx  = (const int*)  d_in[1];
    const float* ew    = (const float*)d_in[2];
    const float* ea    = (const float*)d_in[3];
    const float* w1    = (const float*)d_in[4];
    const float* b1    = (const float*)d_in[5];
    const float* w2    = (const float*)d_in[6];
    const float* b2    = (const float*)d_in[7];
    const float* lin1  = (const float*)d_in[8];
    const float* lin2  = (const float*)d_in[9];
    const float* lin2b = (const float*)d_in[10];
    float* out = (float*)d_out;

    const int N = in_sizes[0] / HF;
    const int E = in_sizes[2] / 3;

    const size_t fN = (size_t)N * HF;
    float* agg    = (float*)d_ws;                    // N*256 f32
    short* y_p    = (short*)(agg + fN);              // N*256 bf16 (pi-permuted)
    short* x_bf   = y_p + fN;                        // N*256 bf16
    int*   cnt    = (int*)(x_bf + fN);
    int*   row    = cnt + N;                         // N+1
    int*   cursor = row + (N + 8);
    int*   perm   = cursor + N;
    short* w1p    = (short*)(((uintptr_t)(perm + E) + 255) & ~(uintptr_t)255);
    short* w2p    = w1p + 16384;                     // 32 KB / 128 KB
    short* lin1p  = w2p + 65536;
    short* lin2p  = lin1p + 65536;

    hipMemsetAsync(cnt, 0, (size_t)N * sizeof(int), stream);

    const int nx8   = (int)(fN / 8);
    const int nAgg4 = (int)(fN / 4);
    const int gConv = (nx8 + 255) / 256;
    const int gHist = (E + 255) / 256;
    const int gZero = (nAgg4 + 255) / 256;
    prep_kernel<<<dim3(104 + gConv + gHist + gZero), dim3(256), 0, stream>>>(
        w1, b1, w2, lin1, lin2, w1p, w2p, lin1p, lin2p, x, x_bf, nx8,
        eidx, cnt, E, agg, nAgg4, gConv, gHist);

    scan_kernel<<<dim3(1), dim3(256), 0, stream>>>(cnt, row, cursor, N, E);

    const int gScatter = (E + 255) / 256;
    const int gNode    = (N + 63) / 64;
    mid_kernel<<<dim3(gScatter + gNode), dim3(256), 0, stream>>>(
        eidx, cursor, perm, E, gScatter, x_bf, lin1p, y_p, N);

    edge_mfma<<<dim3((E + 63) / 64), dim3(256), 0, stream>>>(
        ea, eidx, ew, w1p, w2p, b2, y_p, perm, row, agg, E);

    node2_kernel<<<dim3(gNode), dim3(256), 0, stream>>>(
        agg, lin2p, lin2b, x, out, N);
}

// Round 8
// 317.668 us; speedup vs baseline: 2.0604x; 1.0040x over previous
//
#include <hip/hip_runtime.h>
#include <hip/hip_bf16.h>
#include <stdint.h>

#define HF 256   // H == F == 256
#define GG 50    // G

typedef __attribute__((ext_vector_type(8))) short bf16x8;
typedef __attribute__((ext_vector_type(4))) short bf16x4;
typedef __attribute__((ext_vector_type(4))) float f32x4;

// packed f32x2 -> bf16x2 (v_cvt_pk_bf16_f32 on gfx950), low short = a
__device__ __forceinline__ uint32_t f2bf2u(float a, float b){
    __hip_bfloat162 h = __float22bfloat162_rn(make_float2(a, b));
    union { __hip_bfloat162 h; uint32_t u; } v; v.h = h; return v.u;
}
__device__ __forceinline__ float bf2f(short s){
    union { uint32_t u; float f; } v; v.u = ((uint32_t)(uint16_t)s) << 16;
    return v.f;
}
// shifted softplus: ln(1+e^x) - ln2 (safe for |x| < ~80; GEMM outputs are O(+-6))
__device__ __forceinline__ float ssp_f(float x){
    float e = __builtin_amdgcn_exp2f(x * 1.44269504088896341f);
    return 0.69314718055994531f * __builtin_amdgcn_logf(1.0f + e)
         - 0.69314718055994531f;
}

// ---------------------------------------------------------------------------
// prep_kernel: [pack weights] + [x fp32->bf16] + [degree histogram] + [agg=0]
// B-frag (ntg, kt): lane l holds B[k=kt*32+(l>>4)*8+j][n=ntg*16+(l&15)].
// 8-wave hid perm: pi'(s) = (s>>5)*32 + (s&1)*16 + ((s&31)>>1)
//   (hid storage s = w*32 + l15*2 + nt holds true hidden feature pi'(s))
// w1p: bias b1 folded in as constant-1 row k=50 (zero-pad region of K=64).
// ---------------------------------------------------------------------------
__device__ __forceinline__ void pack_natural(const float* __restrict__ B,
                                             short* __restrict__ Bp,
                                             int idx, int KT, int kmax)
{
    int lane = idx & 63;
    int kt   = (idx >> 6) & (KT - 1);
    int ntg  = idx >> (6 + (KT == 2 ? 1 : 3));
    int col  = ntg * 16 + (lane & 15);
    int k0   = kt * 32 + (lane >> 4) * 8;
    uint32_t u[4];
#pragma unroll
    for (int jj = 0; jj < 4; ++jj) {
        int ka = k0 + 2*jj, kb = ka + 1;
        float a = (ka < kmax) ? B[(size_t)ka * HF + col] : 0.f;
        float b = (kb < kmax) ? B[(size_t)kb * HF + col] : 0.f;
        u[jj] = f2bf2u(a, b);
    }
    *(uint4*)&Bp[(size_t)idx * 8] = *(uint4*)u;
}

__global__ __launch_bounds__(256)
void prep_kernel(const float* __restrict__ w1, const float* __restrict__ b1,
                 const float* __restrict__ w2,
                 const float* __restrict__ lin1, const float* __restrict__ lin2,
                 short* __restrict__ w1p, short* __restrict__ w2p,
                 short* __restrict__ lin1p, short* __restrict__ lin2p,
                 const float* __restrict__ x, short* __restrict__ x_bf, int nx8,
                 const int* __restrict__ eidx, int* __restrict__ cnt, int E,
                 float* __restrict__ agg, int nAgg4, int gConv, int gHist)
{
    int b = blockIdx.x, tid = threadIdx.x;
    if (b < 8) {                       // w1p with b1 folded at k==GG
        int idx  = b * 256 + tid;
        int lane = idx & 63;
        int kt   = (idx >> 6) & 1;
        int ntg  = idx >> 7;
        int col  = ntg * 16 + (lane & 15);
        int k0   = kt * 32 + (lane >> 4) * 8;
        uint32_t u[4];
#pragma unroll
        for (int jj = 0; jj < 4; ++jj) {
            int ka = k0 + 2*jj, kb = ka + 1;
            float va = (ka < GG) ? w1[(size_t)ka * HF + col]
                                 : ((ka == GG) ? b1[col] : 0.f);
            float vb = (kb < GG) ? w1[(size_t)kb * HF + col]
                                 : ((kb == GG) ? b1[col] : 0.f);
            u[jj] = f2bf2u(va, vb);
        }
        *(uint4*)&w1p[(size_t)idx * 8] = *(uint4*)u;
    } else if (b < 40) {               // w2p: permuted k axis (8-wave pi')
        int idx = (b - 8) * 256 + tid;
        int lane = idx & 63;
        int kt   = (idx >> 6) & 7;
        int ntg  = idx >> 9;
        int col  = ntg * 16 + (lane & 15);
        int s0   = kt * 32 + (lane >> 4) * 8;
        uint32_t u[4];
#pragma unroll
        for (int jj = 0; jj < 4; ++jj) {
            int sa = s0 + 2*jj, sb = sa + 1;
            int fa = (sa >> 5) * 32 + (sa & 1) * 16 + ((sa & 31) >> 1);
            int fb = (sb >> 5) * 32 + (sb & 1) * 16 + ((sb & 31) >> 1);
            u[jj] = f2bf2u(w2[(size_t)fa * HF + col], w2[(size_t)fb * HF + col]);
        }
        *(uint4*)&w2p[(size_t)idx * 8] = *(uint4*)u;
    } else if (b < 72) {
        pack_natural(lin1, lin1p, (b - 40) * 256 + tid, 8, HF);
    } else if (b < 104) {
        pack_natural(lin2, lin2p, (b - 72) * 256 + tid, 8, HF);
    } else if (b < 104 + gConv) {      // x -> bf16, 8 elems/thread
        int idx = (b - 104) * 256 + tid;
        if (idx < nx8) {
            const float* xp = x + (size_t)idx * 8;
            float4 p0 = *(const float4*)(xp);
            float4 p1 = *(const float4*)(xp + 4);
            uint32_t u[4] = { f2bf2u(p0.x, p0.y), f2bf2u(p0.z, p0.w),
                              f2bf2u(p1.x, p1.y), f2bf2u(p1.z, p1.w) };
            *(uint4*)&x_bf[(size_t)idx * 8] = *(uint4*)u;
        }
    } else if (b < 104 + gConv + gHist) {   // histogram
        int e = (b - 104 - gConv) * 256 + tid;
        if (e < E) atomicAdd(&cnt[eidx[e]], 1);
    } else {                           // agg zero (float4 granular)
        int idx = (b - 104 - gConv - gHist) * 256 + tid;
        if (idx < nAgg4) ((float4*)agg)[idx] = make_float4(0.f, 0.f, 0.f, 0.f);
    }
}

// ---------------------------------------------------------------------------
// scan_kernel: exclusive scan over cnt -> row/cursor (1 block, LDS scan)
// ---------------------------------------------------------------------------
__global__ __launch_bounds__(256)
void scan_kernel(const int* __restrict__ cnt, int* __restrict__ row,
                 int* __restrict__ cursor, int N, int E)
{
    __shared__ int part[256];
    const int t = threadIdx.x;
    const int CH = (N + 255) / 256;
    int lo = t * CH;
    int hi = min(lo + CH, N);
    int s = 0;
    for (int n = lo; n < hi; ++n) s += cnt[n];
    part[t] = s;
    __syncthreads();
    for (int off = 1; off < 256; off <<= 1) {
        int v = (t >= off) ? part[t - off] : 0;
        __syncthreads();
        part[t] += v;
        __syncthreads();
    }
    int acc = part[t] - s;   // exclusive
    for (int n = lo; n < hi; ++n) {
        row[n] = acc; cursor[n] = acc;
        acc += cnt[n];
    }
    if (t == 255) row[N] = E;
}

// ---------------------------------------------------------------------------
// mid_kernel: [scatter perm] + [node GEMM1: y_p = bf16(pi-perm) x@lin1]
// M-tile 64; y_p stored in the 4-wave pi layout (edge re-indexes into it)
// ---------------------------------------------------------------------------
__global__ __launch_bounds__(256)
void mid_kernel(const int* __restrict__ eidx, int* __restrict__ cursor,
                int* __restrict__ perm, int E, int gScatter,
                const short* __restrict__ x_bf, const short* __restrict__ lin1p,
                short* __restrict__ y_p, int N)
{
    const int tid = threadIdx.x;
    if ((int)blockIdx.x < gScatter) {
        int e = blockIdx.x * 256 + tid;
        if (e < E) {
            int pos = atomicAdd(&cursor[eidx[e]], 1);
            perm[pos] = e;
        }
        return;
    }
    const int blk  = blockIdx.x - gScatter;
    const int lane = tid & 63;
    const int w    = tid >> 6;
    const int l15  = lane & 15;
    const int quad = lane >> 4;
    const int row0 = blk * 64;

    f32x4 acc[4][4];
#pragma unroll
    for (int mt = 0; mt < 4; ++mt)
#pragma unroll
        for (int nt = 0; nt < 4; ++nt) acc[mt][nt] = (f32x4){0.f,0.f,0.f,0.f};

#pragma unroll 2
    for (int kt = 0; kt < 8; ++kt) {
        bf16x8 af[4];
#pragma unroll
        for (int mt = 0; mt < 4; ++mt) {
            int r = row0 + mt * 16 + l15;
            int rl = (r < N) ? r : 0;
            af[mt] = *(const bf16x8*)&x_bf[(size_t)rl * HF + kt * 32 + quad * 8];
        }
#pragma unroll
        for (int nt = 0; nt < 4; ++nt) {
            bf16x8 bfr = *(const bf16x8*)&lin1p[(size_t)(((w*4+nt)*8+kt)*64+lane)*8];
#pragma unroll
            for (int mt = 0; mt < 4; ++mt)
                acc[mt][nt] = __builtin_amdgcn_mfma_f32_16x16x32_bf16(af[mt], bfr, acc[mt][nt], 0, 0, 0);
        }
    }
#pragma unroll
    for (int mt = 0; mt < 4; ++mt) {
#pragma unroll
        for (int r = 0; r < 4; ++r) {
            int row = row0 + mt * 16 + quad * 4 + r;
            if (row < N) {
                uint2 u = make_uint2(f2bf2u(acc[mt][0][r], acc[mt][1][r]),
                                     f2bf2u(acc[mt][2][r], acc[mt][3][r]));
                *(uint2*)&y_p[(size_t)row * HF + w * 64 + l15 * 4] = u;
            }
        }
    }
}

// ---------------------------------------------------------------------------
// node2_kernel: out = ssp(agg@lin2 + b) + x   (M-tile 64)
// ---------------------------------------------------------------------------
__global__ __launch_bounds__(256)
void node2_kernel(const float* __restrict__ agg, const short* __restrict__ lin2p,
                  const float* __restrict__ bias, const float* __restrict__ x,
                  float* __restrict__ out, int N)
{
    const int tid  = threadIdx.x;
    const int lane = tid & 63;
    const int w    = tid >> 6;
    const int l15  = lane & 15;
    const int quad = lane >> 4;
    const int row0 = blockIdx.x * 64;

    f32x4 acc[4][4];
#pragma unroll
    for (int mt = 0; mt < 4; ++mt)
#pragma unroll
        for (int nt = 0; nt < 4; ++nt) acc[mt][nt] = (f32x4){0.f,0.f,0.f,0.f};

#pragma unroll 2
    for (int kt = 0; kt < 8; ++kt) {
        bf16x8 af[4];
#pragma unroll
        for (int mt = 0; mt < 4; ++mt) {
            int r = row0 + mt * 16 + l15;
            int rl = (r < N) ? r : 0;
            const float* ap = agg + (size_t)rl * HF + kt * 32 + quad * 8;
            float4 p0 = *(const float4*)(ap);
            float4 p1 = *(const float4*)(ap + 4);
            union { uint32_t u[4]; bf16x8 v; } c;
            c.u[0] = f2bf2u(p0.x, p0.y); c.u[1] = f2bf2u(p0.z, p0.w);
            c.u[2] = f2bf2u(p1.x, p1.y); c.u[3] = f2bf2u(p1.z, p1.w);
            af[mt] = c.v;
        }
#pragma unroll
        for (int nt = 0; nt < 4; ++nt) {
            bf16x8 bfr = *(const bf16x8*)&lin2p[(size_t)(((w*4+nt)*8+kt)*64+lane)*8];
#pragma unroll
            for (int mt = 0; mt < 4; ++mt)
                acc[mt][nt] = __builtin_amdgcn_mfma_f32_16x16x32_bf16(af[mt], bfr, acc[mt][nt], 0, 0, 0);
        }
    }
    float bs[4];
#pragma unroll
    for (int nt = 0; nt < 4; ++nt) bs[nt] = bias[w * 64 + nt * 16 + l15];
#pragma unroll
    for (int mt = 0; mt < 4; ++mt) {
#pragma unroll
        for (int r = 0; r < 4; ++r) {
            int row = row0 + mt * 16 + quad * 4 + r;
            if (row < N) {
#pragma unroll
                for (int nt = 0; nt < 4; ++nt) {
                    int f = w * 64 + nt * 16 + l15;
                    float v = ssp_f(acc[mt][nt][r] + bs[nt]) + x[(size_t)row * HF + f];
                    out[(size_t)row * HF + f] = v;
                }
            }
        }
    }
}

// ---------------------------------------------------------------------------
// edge_mfma: 8 waves x 32-feature slices over a 64-edge tile (512 threads).
// Per-wave footprint halves vs the 4-wave version: 32 acc AGPR + ~50 VGPR.
// LB(512,6) caps regs at 85/wave -> 3 blocks/CU = 24 waves/CU (6/SIMD),
// +50% latency hiding over the 4-wave/128-reg version's 16 waves, no spill.
// LDS 40448 x 3 = 121 KB. Same total MFMA/VALU work, spread over 2x waves.
//   GEMM1: hid = ssp(ea @ w1 [+b1 k=50 row]) -> LDS (8-wave pi' layout)
//   GEMM2: W = hid @ w2p (pi'-permuted k); msg -> msgT[col][e] (stride 72)
//   GEMM3: segment-sum via selection matrix; per-run f4 stores / atomics
// ---------------------------------------------------------------------------
__global__ __launch_bounds__(512, 6)
void edge_mfma(const float* __restrict__ ea, const int* __restrict__ eidx,
               const float* __restrict__ ew,
               const short* __restrict__ w1p,
               const short* __restrict__ w2p, const float* __restrict__ b2,
               const short* __restrict__ y_p, const int* __restrict__ perm,
               const int* __restrict__ rowp,
               float* __restrict__ agg, int E)
{
    __shared__ short smem[19584];      // 39168 B
    short* ea_b = smem;                // [64][72]   (stage + GEMM1 reads)
    short* hid  = smem;                // [64][264]  (aliases ea_b; barrier-split)
    short* msgT = smem;                // [256][72]  (phase 4+, aliases)
    short* St   = smem + 18432;        // [16][72]
    __shared__ int s_e[64], s_j[64];
    __shared__ float s_c[64];
    __shared__ int s_runnode[64];
    __shared__ unsigned char s_runcomp[64];
    __shared__ unsigned long long s_bmask;
    __shared__ int s_runcnt;

    const int tid  = threadIdx.x;
    const int lane = tid & 63;
    const int w    = tid >> 6;         // 0..7
    const int l15  = lane & 15;
    const int quad = lane >> 4;
    const int e0   = blockIdx.x * 64;

    if (tid < 64) {
        int pp = e0 + tid;
        int e = 0, iv = -1, jv = 0;
        float c = 0.f;
        if (pp < E) {
            e  = perm[pp];
            iv = eidx[e];
            jv = eidx[E + e];
            float d0 = ew[e*3+0], d1 = ew[e*3+1], d2 = ew[e*3+2];
            float d = sqrtf(d0*d0 + d1*d1 + d2*d2);
            c = (d <= 2.0f) ? 0.5f * (__cosf(d * 1.57079632679489662f) + 1.0f) : 0.f;
        }
        s_e[tid] = e; s_j[tid] = jv; s_c[tid] = c;
        int ivn = __shfl_down(iv, 1);
        bool flag = (tid == 63) || (iv != ivn);     // run ends at tid
        unsigned long long m = __ballot(flag);
        if (flag) {
            int rid = (int)__popcll(m & ((1ull << tid) - 1ull));
            s_runnode[rid] = iv;
            int comp = 0;
            if (iv >= 0) {
                int lo = rowp[iv], hi = rowp[iv + 1];
                comp = (lo >= e0 && hi <= e0 + 64) ? 1 : 0;
            }
            s_runcomp[rid] = (unsigned char)comp;
        }
        if (tid == 0) { s_bmask = m; s_runcnt = (int)__popcll(m); }
    }
    __syncthreads();

    // stage edge_attr: float2 loads, pk-convert, dword LDS writes
    for (int idx = tid; idx < 64 * 25; idx += 512) {
        int e = idx / 25, q = idx - e * 25;
        const float* sp = ea + (size_t)s_e[e] * GG + q * 2;
        float2 v = *(const float2*)sp;
        *(uint32_t*)&ea_b[e * 72 + q * 2] = f2bf2u(v.x, v.y);
    }
    for (int idx = tid; idx < 64 * 7; idx += 512) {   // k=50 -> 1.0 (bias row)
        int e = idx / 7, q = idx - e * 7;
        *(uint32_t*)&ea_b[e * 72 + 50 + q * 2] = (q == 0) ? 0x00003F80u : 0u;
    }
    __syncthreads();

    // ---- GEMM1: [64e x 64k] @ [64k x 32f-slice]
    f32x4 acc1[4][2];
#pragma unroll
    for (int mt = 0; mt < 4; ++mt)
#pragma unroll
        for (int nt = 0; nt < 2; ++nt) acc1[mt][nt] = (f32x4){0.f,0.f,0.f,0.f};

#pragma unroll
    for (int kt = 0; kt < 2; ++kt) {
        bf16x8 af[4];
#pragma unroll
        for (int mt = 0; mt < 4; ++mt)
            af[mt] = *(bf16x8*)&ea_b[(mt * 16 + l15) * 72 + kt * 32 + quad * 8];
#pragma unroll
        for (int nt = 0; nt < 2; ++nt) {
            bf16x8 bfr = *(const bf16x8*)&w1p[(size_t)(((w*2+nt)*2+kt)*64+lane)*8];
#pragma unroll
            for (int mt = 0; mt < 4; ++mt)
                acc1[mt][nt] = __builtin_amdgcn_mfma_f32_16x16x32_bf16(af[mt], bfr, acc1[mt][nt], 0, 0, 0);
        }
    }
    __syncthreads();   // ea_b dead; hid (aliased) may be written

    // ssp -> hid (storage s = w*32 + l15*2 + nt holds true feature w*32+nt*16+l15)
#pragma unroll
    for (int mt = 0; mt < 4; ++mt) {
#pragma unroll
        for (int r = 0; r < 4; ++r) {
            int e = mt * 16 + quad * 4 + r;
            float v0 = ssp_f(acc1[mt][0][r]);
            float v1 = ssp_f(acc1[mt][1][r]);
            *(uint32_t*)&hid[e * 264 + w * 32 + l15 * 2] = f2bf2u(v0, v1);
        }
    }
    __syncthreads();

    // ---- GEMM2: [64e x 256k(pi')] @ [256k x 32f-slice]
    f32x4 acc2[4][2];
#pragma unroll
    for (int mt = 0; mt < 4; ++mt)
#pragma unroll
        for (int nt = 0; nt < 2; ++nt) acc2[mt][nt] = (f32x4){0.f,0.f,0.f,0.f};

    __builtin_amdgcn_s_setprio(1);
#pragma unroll 1
    for (int kt = 0; kt < 8; ++kt) {
        bf16x8 af[4];
#pragma unroll
        for (int mt = 0; mt < 4; ++mt)
            af[mt] = *(bf16x8*)&hid[(mt * 16 + l15) * 264 + kt * 32 + quad * 8];
#pragma unroll
        for (int nt = 0; nt < 2; ++nt) {
            bf16x8 bfr = *(const bf16x8*)&w2p[(size_t)(((w*2+nt)*8+kt)*64+lane)*8];
#pragma unroll
            for (int mt = 0; mt < 4; ++mt)
                acc2[mt][nt] = __builtin_amdgcn_mfma_f32_16x16x32_bf16(af[mt], bfr, acc2[mt][nt], 0, 0, 0);
        }
    }
    __builtin_amdgcn_s_setprio(0);

    // ---- y_p gather (after GEMM2: frees regs across peak; drains over barrier)
    // storage pos for true features {w*32+l15, w*32+16+l15} in mid's 4-wave layout
    uint32_t yv[4][4];
    const int ypos = (w >> 1) * 64 + l15 * 4 + (w & 1) * 2;
#pragma unroll
    for (int mt = 0; mt < 4; ++mt)
#pragma unroll
        for (int r = 0; r < 4; ++r) {
            int e = mt * 16 + quad * 4 + r;
            yv[mt][r] = *(const uint32_t*)&y_p[(size_t)s_j[e] * HF + ypos];
        }
    float bias2[2];
#pragma unroll
    for (int nt = 0; nt < 2; ++nt) bias2[nt] = b2[w * 32 + nt * 16 + l15];

    __syncthreads();   // hid dead; msgT/St may now overwrite

    // ---- msg epilogue -> msgT[col][e] (stride 72)
#pragma unroll
    for (int mt = 0; mt < 4; ++mt) {
        float c0 = s_c[mt * 16 + quad * 4 + 0];
        float c1 = s_c[mt * 16 + quad * 4 + 1];
        float c2 = s_c[mt * 16 + quad * 4 + 2];
        float c3 = s_c[mt * 16 + quad * 4 + 3];
#pragma unroll
        for (int nt = 0; nt < 2; ++nt) {
            int col = w * 32 + nt * 16 + l15;
            float y0 = bf2f((short)(nt ? (yv[mt][0] >> 16) : (yv[mt][0] & 0xFFFF)));
            float y1 = bf2f((short)(nt ? (yv[mt][1] >> 16) : (yv[mt][1] & 0xFFFF)));
            float y2 = bf2f((short)(nt ? (yv[mt][2] >> 16) : (yv[mt][2] & 0xFFFF)));
            float y3 = bf2f((short)(nt ? (yv[mt][3] >> 16) : (yv[mt][3] & 0xFFFF)));
            float v0 = (acc2[mt][nt][0] + bias2[nt]) * c0 * y0;
            float v1 = (acc2[mt][nt][1] + bias2[nt]) * c1 * y1;
            float v2 = (acc2[mt][nt][2] + bias2[nt]) * c2 * y2;
            float v3 = (acc2[mt][nt][3] + bias2[nt]) * c3 * y3;
            uint2 u = make_uint2(f2bf2u(v0, v1), f2bf2u(v2, v3));
            *(uint2*)&msgT[col * 72 + mt * 16 + quad * 4] = u;
        }
    }
    // build S^T[run-local][edge] for run group 0 (512 threads: rb covers 8 rows x2)
    {
        unsigned long long bm = s_bmask;
        int e   = tid & 63;
        int rb  = tid >> 6;
        int rid = (int)__popcll(bm & ((1ull << e) - 1ull));
#pragma unroll
        for (int q = 0; q < 2; ++q) {
            int r = rb + q * 8;
            St[r * 72 + e] = (rid == r) ? (short)0x3F80 : (short)0;
        }
    }
    __syncthreads();

    // ---- GEMM3: O[feature][run] = msgT @ S^T, then flush per run
    const int runcnt = s_runcnt;
    for (int ntg = 0; ntg * 16 < runcnt; ++ntg) {
        if (ntg > 0) {   // rare: >16 runs in a tile
            __syncthreads();
            unsigned long long bm = s_bmask;
            int e   = tid & 63;
            int rb  = tid >> 6;
            int rid = (int)__popcll(bm & ((1ull << e) - 1ull));
#pragma unroll
            for (int q = 0; q < 2; ++q) {
                int r = rb + q * 8;
                St[r * 72 + e] = (rid == ntg * 16 + r) ? (short)0x3F80 : (short)0;
            }
            __syncthreads();
        }
        f32x4 acc3[2];
#pragma unroll
        for (int mt = 0; mt < 2; ++mt) acc3[mt] = (f32x4){0.f,0.f,0.f,0.f};
#pragma unroll
        for (int kt = 0; kt < 2; ++kt) {
            bf16x8 bS = *(bf16x8*)&St[l15 * 72 + kt * 32 + quad * 8];
#pragma unroll
            for (int mt = 0; mt < 2; ++mt) {
                bf16x8 af = *(bf16x8*)&msgT[(w*32 + mt*16 + l15) * 72 + kt*32 + quad*8];
                acc3[mt] = __builtin_amdgcn_mfma_f32_16x16x32_bf16(af, bS, acc3[mt], 0, 0, 0);
            }
        }
        // lane owns run r = ntg*16 + l15; features f = w*32 + mt*16 + quad*4 + g
        int r = ntg * 16 + l15;
        if (r < runcnt) {
            int node = s_runnode[r];
            if (node >= 0) {
                float* ap = agg + (size_t)node * HF + w * 32 + quad * 4;
                if (s_runcomp[r]) {
#pragma unroll
                    for (int mt = 0; mt < 2; ++mt) {
                        float4 v = make_float4(acc3[mt][0], acc3[mt][1], acc3[mt][2], acc3[mt][3]);
                        *(float4*)(ap + mt * 16) = v;
                    }
                } else {
#pragma unroll
                    for (int mt = 0; mt < 2; ++mt)
#pragma unroll
                        for (int g = 0; g < 4; ++g)
                            atomicAdd(ap + mt * 16 + g, acc3[mt][g]);
                }
            }
        }
    }
}

// ---------------------------------------------------------------------------
extern "C" void kernel_launch(void* const* d_in, const int* in_sizes, int n_in,
                              void* d_out, int out_size, void* d_ws, size_t ws_size,
                              hipStream_t stream)
{
    const float* x     = (const float*)d_in[0];
    const int*   eidx  = (const int*)  d_in[1];
    const float* ew    = (const float*)d_in[2];
    const float* ea    = (const float*)d_in[3];
    const float* w1    = (const float*)d_in[4];
    const float* b1    = (const float*)d_in[5];
    const float* w2    = (const float*)d_in[6];
    const float* b2    = (const float*)d_in[7];
    const float* lin1  = (const float*)d_in[8];
    const float* lin2  = (const float*)d_in[9];
    const float* lin2b = (const float*)d_in[10];
    float* out = (float*)d_out;

    const int N = in_sizes[0] / HF;
    const int E = in_sizes[2] / 3;

    const size_t fN = (size_t)N * HF;
    float* agg    = (float*)d_ws;                    // N*256 f32
    short* y_p    = (short*)(agg + fN);              // N*256 bf16 (pi-permuted)
    short* x_bf   = y_p + fN;                        // N*256 bf16
    int*   cnt    = (int*)(x_bf + fN);
    int*   row    = cnt + N;                         // N+1
    int*   cursor = row + (N + 8);
    int*   perm   = cursor + N;
    short* w1p    = (short*)(((uintptr_t)(perm + E) + 255) & ~(uintptr_t)255);
    short* w2p    = w1p + 16384;                     // 32 KB / 128 KB
    short* lin1p  = w2p + 65536;
    short* lin2p  = lin1p + 65536;

    hipMemsetAsync(cnt, 0, (size_t)N * sizeof(int), stream);

    const int nx8   = (int)(fN / 8);
    const int nAgg4 = (int)(fN / 4);
    const int gConv = (nx8 + 255) / 256;
    const int gHist = (E + 255) / 256;
    const int gZero = (nAgg4 + 255) / 256;
    prep_kernel<<<dim3(104 + gConv + gHist + gZero), dim3(256), 0, stream>>>(
        w1, b1, w2, lin1, lin2, w1p, w2p, lin1p, lin2p, x, x_bf, nx8,
        eidx, cnt, E, agg, nAgg4, gConv, gHist);

    scan_kernel<<<dim3(1), dim3(256), 0, stream>>>(cnt, row, cursor, N, E);

    const int gScatter = (E + 255) / 256;
    const int gNode    = (N + 63) / 64;
    mid_kernel<<<dim3(gScatter + gNode), dim3(256), 0, stream>>>(
        eidx, cursor, perm, E, gScatter, x_bf, lin1p, y_p, N);

    edge_mfma<<<dim3((E + 63) / 64), dim3(512), 0, stream>>>(
        ea, eidx, ew, w1p, w2p, b2, y_p, perm, row, agg, E);

    node2_kernel<<<dim3(gNode), dim3(256), 0, stream>>>(
        agg, lin2p, lin2b, x, out, N);
}